// Round 1
// baseline (249.030 us; speedup 1.0000x reference)
//
#include <hip/hip_runtime.h>
#include <hip/hip_bf16.h>

typedef __attribute__((ext_vector_type(8))) _Float16 f16x8;
typedef __attribute__((ext_vector_type(8))) short short8;
typedef __attribute__((ext_vector_type(4))) short short4v;
typedef __attribute__((ext_vector_type(4))) float f32x4;

#define LDP 72  // LDS row stride in shorts for 64-wide K tiles (pad vs 64 to spread banks)

__device__ __forceinline__ short f2h(float f) {
  union { _Float16 h; short s; } u; u.h = (_Float16)f; return u.s;
}
__device__ __forceinline__ float h2f(short s) {
  union { short s; _Float16 h; } u; u.s = s; return (float)u.h;
}

// ---------------- weight transpose + f32->f16 ----------------
// WT[l][c=h*128+o][k] = W[l][h][k][o]   (3*512*128)
// WoT[l][d][c]        = Wo[l][c][d]     (3*128*512)
__global__ __launch_bounds__(256) void k_tw(const float* __restrict__ W,
                                            const float* __restrict__ Wo,
                                            short* __restrict__ WT,
                                            short* __restrict__ WoT) {
  int idx = blockIdx.x * 256 + threadIdx.x;
  if (idx < 3 * 512 * 128) {
    int l = idx >> 16, rem = idx & 65535;
    int c = rem >> 7, k = rem & 127;
    int h = c >> 7, o = c & 127;
    WT[idx] = f2h(W[(((l * 4 + h) * 128 + k) << 7) + o]);
  } else {
    int j = idx - 3 * 512 * 128;
    int l = j >> 16, rem = j & 65535;
    int d = rem >> 9, c = rem & 511;
    WoT[j] = f2h(Wo[((l * 512 + c) << 7) + d]);
  }
}

// ---------------- input projection: x = node @ Wp + bp -> f16 ----------------
__global__ __launch_bounds__(256) void k_inproj(const float* __restrict__ nf,
                                                const float* __restrict__ Wp,
                                                const float* __restrict__ bp,
                                                short* __restrict__ xh) {
  int idx = blockIdx.x * 256 + threadIdx.x;  // 16384*128
  int bn = idx >> 7, d = idx & 127;
  float acc = bp[d];
  const float* nr = nf + bn * 7;
#pragma unroll
  for (int i = 0; i < 7; ++i) acc += nr[i] * Wp[(i << 7) + d];
  xh[idx] = f2h(acc);
}

// ---------------- head projection: hT[bh][d][n] = (x @ W[h])^T ----------------
// grid (128 bn-tiles, 4 heads), 256 thr, tile 128x128, BK=64
__global__ __launch_bounds__(256) void k_gemm_h(const short* __restrict__ xh,
                                                const short* __restrict__ WT,
                                                short* __restrict__ hT) {
  __shared__ __align__(16) short As[128 * LDP];
  __shared__ __align__(16) short Bs[128 * LDP];
  const int t = threadIdx.x;
  const int bn0 = blockIdx.x << 7;
  const int head = blockIdx.y;
  const int c0 = head << 7;
  const int w = t >> 6, lane = t & 63, lr = lane & 15, lq = lane >> 4;
  const int wr = w >> 1, wc = w & 1;
  f32x4 acc[4][4] = {};
  for (int k0 = 0; k0 < 128; k0 += 64) {
    const int row = t >> 1, half = (t & 1) << 5;
    {
      const short* sa = xh + ((bn0 + row) << 7) + k0 + half;
      short* da = As + row * LDP + half;
      *(short8*)(da) = *(const short8*)(sa);
      *(short8*)(da + 8) = *(const short8*)(sa + 8);
      *(short8*)(da + 16) = *(const short8*)(sa + 16);
      *(short8*)(da + 24) = *(const short8*)(sa + 24);
      const short* sb = WT + ((c0 + row) << 7) + k0 + half;
      short* db = Bs + row * LDP + half;
      *(short8*)(db) = *(const short8*)(sb);
      *(short8*)(db + 8) = *(const short8*)(sb + 8);
      *(short8*)(db + 16) = *(const short8*)(sb + 16);
      *(short8*)(db + 24) = *(const short8*)(sb + 24);
    }
    __syncthreads();
#pragma unroll
    for (int kk = 0; kk < 2; ++kk) {
      f16x8 a[4], b[4];
#pragma unroll
      for (int m = 0; m < 4; ++m)
        a[m] = *(const f16x8*)(As + (wr * 64 + m * 16 + lr) * LDP + (kk << 5) + (lq << 3));
#pragma unroll
      for (int n = 0; n < 4; ++n)
        b[n] = *(const f16x8*)(Bs + (wc * 64 + n * 16 + lr) * LDP + (kk << 5) + (lq << 3));
#pragma unroll
      for (int m = 0; m < 4; ++m)
#pragma unroll
        for (int n = 0; n < 4; ++n)
          acc[m][n] = __builtin_amdgcn_mfma_f32_16x16x32_f16(a[m], b[n], acc[m][n], 0, 0, 0);
    }
    __syncthreads();
  }
  const int b = bn0 >> 10;
  const int nb = bn0 & 1023;
#pragma unroll
  for (int m = 0; m < 4; ++m) {
    int nrow = nb + wr * 64 + m * 16 + (lq << 2);
#pragma unroll
    for (int n = 0; n < 4; ++n) {
      int d = wc * 64 + n * 16 + lr;
      long base = ((long)((((b << 2) + head) << 7) + d) << 10) + nrow;
      short4v v;
      v[0] = f2h(acc[m][n][0]); v[1] = f2h(acc[m][n][1]);
      v[2] = f2h(acc[m][n][2]); v[3] = f2h(acc[m][n][3]);
      *(short4v*)(hT + base) = v;
    }
  }
}

// ---------------- scores: s1/s2 + per-(b,h) max(s2) ----------------
__global__ __launch_bounds__(256) void k_scores(const short* __restrict__ hT,
                                                const float* __restrict__ a1,
                                                const float* __restrict__ a2,
                                                float* __restrict__ s1,
                                                float* __restrict__ s2,
                                                float* __restrict__ s2max) {
  const int bh = blockIdx.x, h = bh & 3;
  __shared__ float a1s[128], a2s[128], red[4];
  const int t = threadIdx.x;
  if (t < 128) a1s[t] = a1[(h << 7) + t];
  else a2s[t - 128] = a2[(h << 7) + t - 128];
  __syncthreads();
  const int n0 = t << 2;
  float ac1[4] = {}, ac2[4] = {};
  const short* hp = hT + ((long)bh << 17) + n0;
  for (int d = 0; d < 128; ++d) {
    short4v hv = *(const short4v*)(hp + ((long)d << 10));
    float w1 = a1s[d], w2 = a2s[d];
#pragma unroll
    for (int q = 0; q < 4; ++q) {
      float f = h2f(hv[q]);
      ac1[q] += f * w1;
      ac2[q] += f * w2;
    }
  }
  f32x4 v1 = {ac1[0], ac1[1], ac1[2], ac1[3]};
  f32x4 v2 = {ac2[0], ac2[1], ac2[2], ac2[3]};
  *(f32x4*)(s1 + (bh << 10) + n0) = v1;
  *(f32x4*)(s2 + (bh << 10) + n0) = v2;
  float mx = fmaxf(fmaxf(ac2[0], ac2[1]), fmaxf(ac2[2], ac2[3]));
#pragma unroll
  for (int off = 1; off < 64; off <<= 1) mx = fmaxf(mx, __shfl_xor(mx, off));
  if ((t & 63) == 0) red[t >> 6] = mx;
  __syncthreads();
  if (t == 0) s2max[bh] = fmaxf(fmaxf(red[0], red[1]), fmaxf(red[2], red[3]));
}

// ---------------- attention: attn[b][i][h*128+d] = softmax(P) @ h ----------------
// grid (8 i-tiles, 64 bh), 256 thr; P tile [128][64] generated on the fly
__global__ __launch_bounds__(256) void k_attn(const short* __restrict__ hT,
                                              const float* __restrict__ s1,
                                              const float* __restrict__ s2,
                                              const float* __restrict__ s2max,
                                              short* __restrict__ attn) {
  __shared__ __align__(16) short Ps[128 * LDP];
  __shared__ __align__(16) short Hs[128 * LDP];
  __shared__ float s1a[128], mis[128], dps[256], den[128];
  const int it = blockIdx.x, bh = blockIdx.y;
  const int i0 = it << 7;
  const int t = threadIdx.x;
  if (t < 128) {
    float s1v = s1[(bh << 10) + i0 + t];
    float tv = s1v + s2max[bh];
    s1a[t] = s1v;
    mis[t] = tv > 0.f ? tv : 0.2f * tv;  // upper bound of row max (lrelu monotone)
  }
  __syncthreads();
  const int ip = t >> 1, jh = (t & 1) << 5;
  const float s1i = s1a[ip], mi = mis[ip];
  const int ig = i0 + ip;
  float dsum = 0.f;
  const int w = t >> 6, lane = t & 63, lr = lane & 15, lq = lane >> 4;
  const int wr = w >> 1, wc = w & 1;
  f32x4 acc[4][4] = {};
  const float* s2g = s2 + (bh << 10);
  const short* hTb = hT + ((long)bh << 17);
  const int dd = t >> 2, chunk = (t & 3) << 4;
  for (int j0 = 0; j0 < 1024; j0 += 64) {
    {  // stage Hs[d][j] from hT rows (no transpose needed)
      const short* sp0 = hTb + ((long)dd << 10) + j0 + chunk;
      short* dp0 = Hs + dd * LDP + chunk;
      *(short8*)(dp0) = *(const short8*)(sp0);
      *(short8*)(dp0 + 8) = *(const short8*)(sp0 + 8);
      const short* sp1 = hTb + ((long)(dd + 64) << 10) + j0 + chunk;
      short* dp1 = Hs + (dd + 64) * LDP + chunk;
      *(short8*)(dp1) = *(const short8*)(sp1);
      *(short8*)(dp1 + 8) = *(const short8*)(sp1 + 8);
    }
    {  // generate P tile: thread handles row ip, j in [jh, jh+32)
      const float* s2t = s2g + j0 + jh;
#pragma unroll
      for (int qq = 0; qq < 4; ++qq) {
        f32x4 sa = *(const f32x4*)(s2t + (qq << 3));
        f32x4 sb = *(const f32x4*)(s2t + (qq << 3) + 4);
        short8 v;
#pragma unroll
        for (int e = 0; e < 8; ++e) {
          float sv = e < 4 ? sa[e] : sb[e - 4];
          float tv = s1i + sv;
          float ee = tv > 0.f ? tv : 0.2f * tv;
          float p = __expf(ee - mi);
          if (ig == j0 + jh + (qq << 3) + e) p = 0.f;  // mask diagonal
          dsum += p;
          v[e] = f2h(p);
        }
        *(short8*)(Ps + ip * LDP + jh + (qq << 3)) = v;
      }
    }
    __syncthreads();
#pragma unroll
    for (int kk = 0; kk < 2; ++kk) {
      f16x8 a[4], b[4];
#pragma unroll
      for (int m = 0; m < 4; ++m)
        a[m] = *(const f16x8*)(Ps + (wr * 64 + m * 16 + lr) * LDP + (kk << 5) + (lq << 3));
#pragma unroll
      for (int n = 0; n < 4; ++n)
        b[n] = *(const f16x8*)(Hs + (wc * 64 + n * 16 + lr) * LDP + (kk << 5) + (lq << 3));
#pragma unroll
      for (int m = 0; m < 4; ++m)
#pragma unroll
        for (int n = 0; n < 4; ++n)
          acc[m][n] = __builtin_amdgcn_mfma_f32_16x16x32_f16(a[m], b[n], acc[m][n], 0, 0, 0);
    }
    __syncthreads();
  }
  dps[(ip << 1) | (t & 1)] = dsum;
  __syncthreads();
  if (t < 128) den[t] = 1.f / (dps[t << 1] + dps[(t << 1) + 1]);
  __syncthreads();
  const int b = bh >> 2, head = bh & 3;
#pragma unroll
  for (int m = 0; m < 4; ++m) {
    f32x4 d4 = *(const f32x4*)&den[wr * 64 + m * 16 + (lq << 2)];
    int irow = i0 + wr * 64 + m * 16 + (lq << 2);
#pragma unroll
    for (int n = 0; n < 4; ++n) {
      int d = wc * 64 + n * 16 + lr;
      long base = ((long)((b << 10) + irow) << 9) + (head << 7) + d;
      attn[base] = f2h(acc[m][n][0] * d4[0]);
      attn[base + 512] = f2h(acc[m][n][1] * d4[1]);
      attn[base + 1024] = f2h(acc[m][n][2] * d4[2]);
      attn[base + 1536] = f2h(acc[m][n][3] * d4[3]);
    }
  }
}

// ---------------- out-proj + bias (+residual) + LN (+relu) ----------------
// grid 256 blocks x 256 thr; tile 64 rows x 128 cols; each wave owns 16 full rows
template <int HAS_RES, int DO_RELU, int WRITE_OUT>
__global__ __launch_bounds__(256) void k_outproj(const short* __restrict__ attn,
                                                 const short* __restrict__ WoT,
                                                 const float* __restrict__ bo,
                                                 const float* __restrict__ gamma,
                                                 const float* __restrict__ beta,
                                                 float* __restrict__ xf,
                                                 short* __restrict__ xh,
                                                 float* __restrict__ outp) {
  __shared__ __align__(16) short As[64 * LDP];
  __shared__ __align__(16) short Bs[128 * LDP];
  const int t = threadIdx.x;
  const int bn0 = blockIdx.x << 6;
  const int w = t >> 6, lane = t & 63, lr = lane & 15, lq = lane >> 4;
  f32x4 acc[8] = {};
  const int rowA = t >> 2, chA = (t & 3) << 4;
  const int rowB = t >> 1, chB = (t & 1) << 5;
  for (int k0 = 0; k0 < 512; k0 += 64) {
    {
      const short* sa = attn + ((long)(bn0 + rowA) << 9) + k0 + chA;
      short* da = As + rowA * LDP + chA;
      *(short8*)(da) = *(const short8*)(sa);
      *(short8*)(da + 8) = *(const short8*)(sa + 8);
      const short* sb = WoT + (rowB << 9) + k0 + chB;
      short* db = Bs + rowB * LDP + chB;
      *(short8*)(db) = *(const short8*)(sb);
      *(short8*)(db + 8) = *(const short8*)(sb + 8);
      *(short8*)(db + 16) = *(const short8*)(sb + 16);
      *(short8*)(db + 24) = *(const short8*)(sb + 24);
    }
    __syncthreads();
#pragma unroll
    for (int kk = 0; kk < 2; ++kk) {
      f16x8 a = *(const f16x8*)(As + ((w << 4) + lr) * LDP + (kk << 5) + (lq << 3));
#pragma unroll
      for (int n = 0; n < 8; ++n) {
        f16x8 b = *(const f16x8*)(Bs + ((n << 4) + lr) * LDP + (kk << 5) + (lq << 3));
        acc[n] = __builtin_amdgcn_mfma_f32_16x16x32_f16(a, b, acc[n], 0, 0, 0);
      }
    }
    __syncthreads();
  }
  float v[8][4], gam[8], bet[8];
#pragma unroll
  for (int n = 0; n < 8; ++n) {
    int d = (n << 4) + lr;
    float bv = bo[d];
    gam[n] = gamma[d];
    bet[n] = beta[d];
#pragma unroll
    for (int r = 0; r < 4; ++r) {
      float x = acc[n][r] + bv;
      if (HAS_RES) x += xf[((bn0 + (w << 4) + (lq << 2) + r) << 7) + d];
      v[n][r] = x;
    }
  }
#pragma unroll
  for (int r = 0; r < 4; ++r) {
    float s = 0.f, q = 0.f;
#pragma unroll
    for (int n = 0; n < 8; ++n) { s += v[n][r]; q += v[n][r] * v[n][r]; }
#pragma unroll
    for (int mk = 1; mk < 16; mk <<= 1) { s += __shfl_xor(s, mk); q += __shfl_xor(q, mk); }
    float mean = s * 0.0078125f;
    float var = q * 0.0078125f - mean * mean;
    float rstd = rsqrtf(var + 1e-5f);
    int row = bn0 + (w << 4) + (lq << 2) + r;
#pragma unroll
    for (int n = 0; n < 8; ++n) {
      int d = (n << 4) + lr;
      float o = (v[n][r] - mean) * rstd * gam[n] + bet[n];
      if (DO_RELU) o = fmaxf(o, 0.f);
      if (WRITE_OUT) {
        outp[(row << 7) + d] = o;
      } else {
        xh[(row << 7) + d] = f2h(o);
        xf[(row << 7) + d] = o;
      }
    }
  }
}

extern "C" void kernel_launch(void* const* d_in, const int* in_sizes, int n_in,
                              void* d_out, int out_size, void* d_ws, size_t ws_size,
                              hipStream_t stream) {
  const float* nf = (const float*)d_in[0];
  const float* Wp = (const float*)d_in[1];
  const float* bp = (const float*)d_in[2];
  const float* W = (const float*)d_in[3];
  const float* a1 = (const float*)d_in[4];
  const float* a2 = (const float*)d_in[5];
  const float* Wo = (const float*)d_in[6];
  const float* bo = (const float*)d_in[7];
  const float* gamma = (const float*)d_in[8];
  const float* beta = (const float*)d_in[9];
  float* outp = (float*)d_out;

  char* ws = (char*)d_ws;
  short* xh = (short*)(ws);                              // 4 MB  [16384][128] f16
  float* xf = (float*)(ws + (4ll << 20));                // 8 MB  [16384][128] f32
  short* hT = (short*)(ws + (12ll << 20));               // 16 MB [64][128][1024] f16
  short* attn = (short*)(ws + (28ll << 20));             // 16 MB [16384][512] f16
  float* s1 = (float*)(ws + (44ll << 20));               // 256 KB
  float* s2 = (float*)(ws + (44ll << 20) + 262144);      // 256 KB
  float* s2m = (float*)(ws + (44ll << 20) + 524288);     // 256 B
  short* WT = (short*)(ws + (45ll << 20));               // 384 KB [3][512][128] f16
  short* WoT = (short*)(ws + (45ll << 20) + 393216);     // 384 KB [3][128][512] f16

  k_tw<<<1536, 256, 0, stream>>>(W, Wo, WT, WoT);
  k_inproj<<<8192, 256, 0, stream>>>(nf, Wp, bp, xh);
  for (int l = 0; l < 3; ++l) {
    k_gemm_h<<<dim3(128, 4), 256, 0, stream>>>(xh, WT + l * 65536, hT);
    k_scores<<<64, 256, 0, stream>>>(hT, a1 + l * 512, a2 + l * 512, s1, s2, s2m);
    k_attn<<<dim3(8, 64), 256, 0, stream>>>(hT, s1, s2, s2m, attn);
    if (l == 0)
      k_outproj<0, 1, 0><<<256, 256, 0, stream>>>(attn, WoT + l * 65536, bo + l * 128,
                                                  gamma + l * 128, beta + l * 128, xf, xh, outp);
    else if (l == 1)
      k_outproj<1, 1, 0><<<256, 256, 0, stream>>>(attn, WoT + l * 65536, bo + l * 128,
                                                  gamma + l * 128, beta + l * 128, xf, xh, outp);
    else
      k_outproj<1, 0, 1><<<256, 256, 0, stream>>>(attn, WoT + l * 65536, bo + l * 128,
                                                  gamma + l * 128, beta + l * 128, xf, xh, outp);
  }
}

// Round 2
// 239.709 us; speedup vs baseline: 1.0389x; 1.0389x over previous
//
#include <hip/hip_runtime.h>
#include <hip/hip_bf16.h>

typedef __attribute__((ext_vector_type(8))) _Float16 f16x8;
typedef __attribute__((ext_vector_type(8))) short short8;
typedef __attribute__((ext_vector_type(4))) short short4v;
typedef __attribute__((ext_vector_type(4))) float f32x4;

#define LDP 72   // LDS row stride (shorts) for reg-staged tiles (pad to spread banks)
#define LDH 64   // Hs row stride (shorts): linear, required by global_load_lds
#define LDPP 72  // Ps row stride (shorts)

typedef const __attribute__((address_space(1))) unsigned int* gas_ptr;
typedef __attribute__((address_space(3))) unsigned int* las_ptr;
#define GLDS16(gp, lp) \
  __builtin_amdgcn_global_load_lds((gas_ptr)(gp), (las_ptr)(lp), 16, 0, 0)

__device__ __forceinline__ short f2h(float f) {
  union { _Float16 h; short s; } u; u.h = (_Float16)f; return u.s;
}
__device__ __forceinline__ float h2f(short s) {
  union { short s; _Float16 h; } u; u.s = s; return (float)u.h;
}

// ---------------- weight transpose + f32->f16 ----------------
__global__ __launch_bounds__(256) void k_tw(const float* __restrict__ W,
                                            const float* __restrict__ Wo,
                                            short* __restrict__ WT,
                                            short* __restrict__ WoT) {
  int idx = blockIdx.x * 256 + threadIdx.x;
  if (idx < 3 * 512 * 128) {
    int l = idx >> 16, rem = idx & 65535;
    int c = rem >> 7, k = rem & 127;
    int h = c >> 7, o = c & 127;
    WT[idx] = f2h(W[(((l * 4 + h) * 128 + k) << 7) + o]);
  } else {
    int j = idx - 3 * 512 * 128;
    int l = j >> 16, rem = j & 65535;
    int d = rem >> 9, c = rem & 511;
    WoT[j] = f2h(Wo[((l * 512 + c) << 7) + d]);
  }
}

// ---------------- input projection ----------------
__global__ __launch_bounds__(256) void k_inproj(const float* __restrict__ nf,
                                                const float* __restrict__ Wp,
                                                const float* __restrict__ bp,
                                                short* __restrict__ xh) {
  int idx = blockIdx.x * 256 + threadIdx.x;
  int bn = idx >> 7, d = idx & 127;
  float acc = bp[d];
  const float* nr = nf + bn * 7;
#pragma unroll
  for (int i = 0; i < 7; ++i) acc += nr[i] * Wp[(i << 7) + d];
  xh[idx] = f2h(acc);
}

// ---------------- head projection: hT[bh][d][n] = (x @ W[h])^T ----------------
__global__ __launch_bounds__(256) void k_gemm_h(const short* __restrict__ xh,
                                                const short* __restrict__ WT,
                                                short* __restrict__ hT) {
  __shared__ __align__(16) short As[128 * LDP];
  __shared__ __align__(16) short Bs[128 * LDP];
  const int t = threadIdx.x;
  const int bn0 = blockIdx.x << 7;
  const int head = blockIdx.y;
  const int c0 = head << 7;
  const int w = t >> 6, lane = t & 63, lr = lane & 15, lq = lane >> 4;
  const int wr = w >> 1, wc = w & 1;
  f32x4 acc[4][4] = {};
  for (int k0 = 0; k0 < 128; k0 += 64) {
    const int row = t >> 1, half = (t & 1) << 5;
    {
      const short* sa = xh + ((bn0 + row) << 7) + k0 + half;
      short* da = As + row * LDP + half;
      *(short8*)(da) = *(const short8*)(sa);
      *(short8*)(da + 8) = *(const short8*)(sa + 8);
      *(short8*)(da + 16) = *(const short8*)(sa + 16);
      *(short8*)(da + 24) = *(const short8*)(sa + 24);
      const short* sb = WT + ((c0 + row) << 7) + k0 + half;
      short* db = Bs + row * LDP + half;
      *(short8*)(db) = *(const short8*)(sb);
      *(short8*)(db + 8) = *(const short8*)(sb + 8);
      *(short8*)(db + 16) = *(const short8*)(sb + 16);
      *(short8*)(db + 24) = *(const short8*)(sb + 24);
    }
    __syncthreads();
#pragma unroll
    for (int kk = 0; kk < 2; ++kk) {
      f16x8 a[4], b[4];
#pragma unroll
      for (int m = 0; m < 4; ++m)
        a[m] = *(const f16x8*)(As + (wr * 64 + m * 16 + lr) * LDP + (kk << 5) + (lq << 3));
#pragma unroll
      for (int n = 0; n < 4; ++n)
        b[n] = *(const f16x8*)(Bs + (wc * 64 + n * 16 + lr) * LDP + (kk << 5) + (lq << 3));
#pragma unroll
      for (int m = 0; m < 4; ++m)
#pragma unroll
        for (int n = 0; n < 4; ++n)
          acc[m][n] = __builtin_amdgcn_mfma_f32_16x16x32_f16(a[m], b[n], acc[m][n], 0, 0, 0);
    }
    __syncthreads();
  }
  const int b = bn0 >> 10;
  const int nb = bn0 & 1023;
#pragma unroll
  for (int m = 0; m < 4; ++m) {
    int nrow = nb + wr * 64 + m * 16 + (lq << 2);
#pragma unroll
    for (int n = 0; n < 4; ++n) {
      int d = wc * 64 + n * 16 + lr;
      long base = ((long)((((b << 2) + head) << 7) + d) << 10) + nrow;
      short4v v;
      v[0] = f2h(acc[m][n][0]); v[1] = f2h(acc[m][n][1]);
      v[2] = f2h(acc[m][n][2]); v[3] = f2h(acc[m][n][3]);
      *(short4v*)(hT + base) = v;
    }
  }
}

// ---------------- scores ----------------
__global__ __launch_bounds__(256) void k_scores(const short* __restrict__ hT,
                                                const float* __restrict__ a1,
                                                const float* __restrict__ a2,
                                                float* __restrict__ s1,
                                                float* __restrict__ s2,
                                                float* __restrict__ s2max) {
  const int bh = blockIdx.x, h = bh & 3;
  __shared__ float a1s[128], a2s[128], red[4];
  const int t = threadIdx.x;
  if (t < 128) a1s[t] = a1[(h << 7) + t];
  else a2s[t - 128] = a2[(h << 7) + t - 128];
  __syncthreads();
  const int n0 = t << 2;
  float ac1[4] = {}, ac2[4] = {};
  const short* hp = hT + ((long)bh << 17) + n0;
  for (int d = 0; d < 128; ++d) {
    short4v hv = *(const short4v*)(hp + ((long)d << 10));
    float w1 = a1s[d], w2 = a2s[d];
#pragma unroll
    for (int q = 0; q < 4; ++q) {
      float f = h2f(hv[q]);
      ac1[q] += f * w1;
      ac2[q] += f * w2;
    }
  }
  f32x4 v1 = {ac1[0], ac1[1], ac1[2], ac1[3]};
  f32x4 v2 = {ac2[0], ac2[1], ac2[2], ac2[3]};
  *(f32x4*)(s1 + (bh << 10) + n0) = v1;
  *(f32x4*)(s2 + (bh << 10) + n0) = v2;
  float mx = fmaxf(fmaxf(ac2[0], ac2[1]), fmaxf(ac2[2], ac2[3]));
#pragma unroll
  for (int off = 1; off < 64; off <<= 1) mx = fmaxf(mx, __shfl_xor(mx, off));
  if ((t & 63) == 0) red[t >> 6] = mx;
  __syncthreads();
  if (t == 0) s2max[bh] = fmaxf(fmaxf(red[0], red[1]), fmaxf(red[2], red[3]));
}

// ---------------- attention ----------------
// grid (64 bh, 8 it) so all i-tiles of one bh share an XCD (L2 locality).
// Double-buffered Hs (glds, swizzled source) + Ps (P-gen), 1 barrier/iter.
__global__ __launch_bounds__(256) void k_attn(const short* __restrict__ hT,
                                              const float* __restrict__ s1,
                                              const float* __restrict__ s2,
                                              const float* __restrict__ s2max,
                                              short* __restrict__ attn) {
  __shared__ __align__(16) short Ps[2][128 * LDPP];
  __shared__ __align__(16) short Hs[2][128 * LDH];
  __shared__ float s1a[128], mis[128], dps[256], den[128];
  const int bh = blockIdx.x, it = blockIdx.y;
  const int i0 = it << 7;
  const int t = threadIdx.x;
  if (t < 128) {
    float s1v = s1[(bh << 10) + i0 + t];
    float tv = s1v + s2max[bh];
    s1a[t] = s1v;
    mis[t] = tv > 0.f ? tv : 0.2f * tv;  // upper bound of row max (lrelu monotone)
  }
  __syncthreads();
  const int ip = t >> 1, jh = (t & 1) << 5;
  const float s1i = s1a[ip], mi = mis[ip];
  const int ig = i0 + ip;
  float dsum = 0.f;
  const int w = t >> 6, lane = t & 63, lr = lane & 15, lq = lane >> 4;
  const int wr = w >> 1, wc = w & 1;
  f32x4 acc[4][4] = {};
  const float* s2g = s2 + (bh << 10);
  const short* hTb = hT + ((long)bh << 17);
  // glds: lane covers row grow(+8 per instr), 16B chunk pre-swizzled so LDS
  // stays linear while reads use slot = chunk ^ (row&7)  (rule 21 both-sides)
  const int grow = (w << 5) + (lane >> 3);
  const int gcol = ((lane & 7) ^ (lane >> 3)) << 3;
  const short* gsrc = hTb + ((long)grow << 10) + gcol;

#define STAGE(buf, J0)                                              \
  do {                                                              \
    short* ldsb = &Hs[buf][(w << 5) * LDH];                         \
    _Pragma("unroll") for (int i_ = 0; i_ < 4; ++i_)                \
        GLDS16(gsrc + ((long)(i_ << 3) << 10) + (J0),               \
               ldsb + i_ * 8 * LDH);                                \
  } while (0)

#define PGEN(buf, J0)                                               \
  do {                                                              \
    const float* s2t = s2g + (J0) + jh;                             \
    short* pd = &Ps[buf][ip * LDPP + jh];                           \
    _Pragma("unroll") for (int qq = 0; qq < 4; ++qq) {              \
      f32x4 sa = *(const f32x4*)(s2t + (qq << 3));                  \
      f32x4 sb = *(const f32x4*)(s2t + (qq << 3) + 4);              \
      short8 v;                                                     \
      _Pragma("unroll") for (int e = 0; e < 8; ++e) {               \
        float sv = e < 4 ? sa[e] : sb[e - 4];                       \
        float tv = s1i + sv;                                        \
        float ee = fmaxf(tv, 0.2f * tv);                            \
        float p = __expf(ee - mi);                                  \
        if (ig == (J0) + jh + (qq << 3) + e) p = 0.f;               \
        dsum += p;                                                  \
        v[e] = f2h(p);                                              \
      }                                                             \
      *(short8*)(pd + (qq << 3)) = v;                               \
    }                                                               \
  } while (0)

#define MM(buf)                                                             \
  do {                                                                      \
    _Pragma("unroll") for (int kk = 0; kk < 2; ++kk) {                      \
      f16x8 a[4], b[4];                                                     \
      _Pragma("unroll") for (int m = 0; m < 4; ++m)                         \
          a[m] = *(const f16x8*)(&Ps[buf][(wr * 64 + m * 16 + lr) * LDPP +  \
                                          (kk << 5) + (lq << 3)]);          \
      _Pragma("unroll") for (int n = 0; n < 4; ++n) {                       \
        int r_ = wc * 64 + n * 16 + lr;                                     \
        int slot_ = ((kk << 2) + lq) ^ (r_ & 7);                            \
        b[n] = *(const f16x8*)(&Hs[buf][r_ * LDH + (slot_ << 3)]);          \
      }                                                                     \
      _Pragma("unroll") for (int m = 0; m < 4; ++m)                         \
          _Pragma("unroll") for (int n = 0; n < 4; ++n)                     \
              acc[m][n] = __builtin_amdgcn_mfma_f32_16x16x32_f16(           \
                  a[m], b[n], acc[m][n], 0, 0, 0);                          \
    }                                                                       \
  } while (0)

  STAGE(0, 0);
  PGEN(0, 0);
  __syncthreads();
  for (int jt = 0; jt < 15; ++jt) {
    const int cur = jt & 1, nxt = cur ^ 1;
    const int jn = (jt + 1) << 6;
    STAGE(nxt, jn);                     // async, drains at this iter's barrier
    __builtin_amdgcn_s_setprio(1);
    MM(cur);
    __builtin_amdgcn_s_setprio(0);
    PGEN(nxt, jn);                      // exp on VALU overlaps matrix pipe
    __syncthreads();
  }
  MM(1);

  dps[t] = dsum;
  __syncthreads();
  if (t < 128) den[t] = 1.f / (dps[t << 1] + dps[(t << 1) + 1]);
  __syncthreads();
  const int b = bh >> 2, head = bh & 3;
#pragma unroll
  for (int m = 0; m < 4; ++m) {
    f32x4 d4 = *(const f32x4*)&den[wr * 64 + m * 16 + (lq << 2)];
    int irow = i0 + wr * 64 + m * 16 + (lq << 2);
#pragma unroll
    for (int n = 0; n < 4; ++n) {
      int d = wc * 64 + n * 16 + lr;
      long base = ((long)((b << 10) + irow) << 9) + (head << 7) + d;
      attn[base] = f2h(acc[m][n][0] * d4[0]);
      attn[base + 512] = f2h(acc[m][n][1] * d4[1]);
      attn[base + 1024] = f2h(acc[m][n][2] * d4[2]);
      attn[base + 1536] = f2h(acc[m][n][3] * d4[3]);
    }
  }
#undef STAGE
#undef PGEN
#undef MM
}

// ---------------- out-proj + bias (+residual) + LN (+relu) ----------------
template <int HAS_RES, int DO_RELU, int WRITE_OUT>
__global__ __launch_bounds__(256) void k_outproj(const short* __restrict__ attn,
                                                 const short* __restrict__ WoT,
                                                 const float* __restrict__ bo,
                                                 const float* __restrict__ gamma,
                                                 const float* __restrict__ beta,
                                                 float* __restrict__ xf,
                                                 short* __restrict__ xh,
                                                 float* __restrict__ outp) {
  __shared__ __align__(16) short As[64 * LDP];
  __shared__ __align__(16) short Bs[128 * LDP];
  const int t = threadIdx.x;
  const int bn0 = blockIdx.x << 6;
  const int w = t >> 6, lane = t & 63, lr = lane & 15, lq = lane >> 4;
  f32x4 acc[8] = {};
  const int rowA = t >> 2, chA = (t & 3) << 4;
  const int rowB = t >> 1, chB = (t & 1) << 5;
  for (int k0 = 0; k0 < 512; k0 += 64) {
    {
      const short* sa = attn + ((long)(bn0 + rowA) << 9) + k0 + chA;
      short* da = As + rowA * LDP + chA;
      *(short8*)(da) = *(const short8*)(sa);
      *(short8*)(da + 8) = *(const short8*)(sa + 8);
      const short* sb = WoT + (rowB << 9) + k0 + chB;
      short* db = Bs + rowB * LDP + chB;
      *(short8*)(db) = *(const short8*)(sb);
      *(short8*)(db + 8) = *(const short8*)(sb + 8);
      *(short8*)(db + 16) = *(const short8*)(sb + 16);
      *(short8*)(db + 24) = *(const short8*)(sb + 24);
    }
    __syncthreads();
#pragma unroll
    for (int kk = 0; kk < 2; ++kk) {
      f16x8 a = *(const f16x8*)(As + ((w << 4) + lr) * LDP + (kk << 5) + (lq << 3));
#pragma unroll
      for (int n = 0; n < 8; ++n) {
        f16x8 b = *(const f16x8*)(Bs + ((n << 4) + lr) * LDP + (kk << 5) + (lq << 3));
        acc[n] = __builtin_amdgcn_mfma_f32_16x16x32_f16(a, b, acc[n], 0, 0, 0);
      }
    }
    __syncthreads();
  }
  float v[8][4], gam[8], bet[8];
#pragma unroll
  for (int n = 0; n < 8; ++n) {
    int d = (n << 4) + lr;
    float bv = bo[d];
    gam[n] = gamma[d];
    bet[n] = beta[d];
#pragma unroll
    for (int r = 0; r < 4; ++r) {
      float x = acc[n][r] + bv;
      if (HAS_RES) x += xf[((bn0 + (w << 4) + (lq << 2) + r) << 7) + d];
      v[n][r] = x;
    }
  }
#pragma unroll
  for (int r = 0; r < 4; ++r) {
    float s = 0.f, q = 0.f;
#pragma unroll
    for (int n = 0; n < 8; ++n) { s += v[n][r]; q += v[n][r] * v[n][r]; }
#pragma unroll
    for (int mk = 1; mk < 16; mk <<= 1) { s += __shfl_xor(s, mk); q += __shfl_xor(q, mk); }
    float mean = s * 0.0078125f;
    float var = q * 0.0078125f - mean * mean;
    float rstd = rsqrtf(var + 1e-5f);
    int row = bn0 + (w << 4) + (lq << 2) + r;
#pragma unroll
    for (int n = 0; n < 8; ++n) {
      int d = (n << 4) + lr;
      float o = (v[n][r] - mean) * rstd * gam[n] + bet[n];
      if (DO_RELU) o = fmaxf(o, 0.f);
      if (WRITE_OUT) {
        outp[(row << 7) + d] = o;
      } else {
        xh[(row << 7) + d] = f2h(o);
        xf[(row << 7) + d] = o;
      }
    }
  }
}

extern "C" void kernel_launch(void* const* d_in, const int* in_sizes, int n_in,
                              void* d_out, int out_size, void* d_ws, size_t ws_size,
                              hipStream_t stream) {
  const float* nf = (const float*)d_in[0];
  const float* Wp = (const float*)d_in[1];
  const float* bp = (const float*)d_in[2];
  const float* W = (const float*)d_in[3];
  const float* a1 = (const float*)d_in[4];
  const float* a2 = (const float*)d_in[5];
  const float* Wo = (const float*)d_in[6];
  const float* bo = (const float*)d_in[7];
  const float* gamma = (const float*)d_in[8];
  const float* beta = (const float*)d_in[9];
  float* outp = (float*)d_out;

  char* ws = (char*)d_ws;
  short* xh = (short*)(ws);
  float* xf = (float*)(ws + (4ll << 20));
  short* hT = (short*)(ws + (12ll << 20));
  short* attn = (short*)(ws + (28ll << 20));
  float* s1 = (float*)(ws + (44ll << 20));
  float* s2 = (float*)(ws + (44ll << 20) + 262144);
  float* s2m = (float*)(ws + (44ll << 20) + 524288);
  short* WT = (short*)(ws + (45ll << 20));
  short* WoT = (short*)(ws + (45ll << 20) + 393216);

  k_tw<<<1536, 256, 0, stream>>>(W, Wo, WT, WoT);
  k_inproj<<<8192, 256, 0, stream>>>(nf, Wp, bp, xh);
  for (int l = 0; l < 3; ++l) {
    k_gemm_h<<<dim3(128, 4), 256, 0, stream>>>(xh, WT + l * 65536, hT);
    k_scores<<<64, 256, 0, stream>>>(hT, a1 + l * 512, a2 + l * 512, s1, s2, s2m);
    k_attn<<<dim3(64, 8), 256, 0, stream>>>(hT, s1, s2, s2m, attn);
    if (l == 0)
      k_outproj<0, 1, 0><<<256, 256, 0, stream>>>(attn, WoT + l * 65536, bo + l * 128,
                                                  gamma + l * 128, beta + l * 128, xf, xh, outp);
    else if (l == 1)
      k_outproj<1, 1, 0><<<256, 256, 0, stream>>>(attn, WoT + l * 65536, bo + l * 128,
                                                  gamma + l * 128, beta + l * 128, xf, xh, outp);
    else
      k_outproj<1, 0, 1><<<256, 256, 0, stream>>>(attn, WoT + l * 65536, bo + l * 128,
                                                  gamma + l * 128, beta + l * 128, xf, xh, outp);
  }
}

// Round 3
// 184.911 us; speedup vs baseline: 1.3468x; 1.2963x over previous
//
#include <hip/hip_runtime.h>
#include <hip/hip_bf16.h>

typedef __attribute__((ext_vector_type(8))) _Float16 f16x8;
typedef __attribute__((ext_vector_type(8))) short short8;
typedef __attribute__((ext_vector_type(4))) short short4v;
typedef __attribute__((ext_vector_type(4))) float f32x4;

#define LDP 72   // LDS row stride (shorts) for reg-staged GEMM tiles
#define LDH 64   // Hs row stride (shorts): linear, required by global_load_lds

typedef const __attribute__((address_space(1))) unsigned int* gas_ptr;
typedef __attribute__((address_space(3))) unsigned int* las_ptr;
#define GLDS16(gp, lp) \
  __builtin_amdgcn_global_load_lds((gas_ptr)(gp), (las_ptr)(lp), 16, 0, 0)

__device__ __forceinline__ short f2h(float f) {
  union { _Float16 h; short s; } u; u.h = (_Float16)f; return u.s;
}
__device__ __forceinline__ float h2f(short s) {
  union { short s; _Float16 h; } u; u.s = s; return (float)u.h;
}

// ---------------- weight transpose + f32->f16 ----------------
__global__ __launch_bounds__(256) void k_tw(const float* __restrict__ W,
                                            const float* __restrict__ Wo,
                                            short* __restrict__ WT,
                                            short* __restrict__ WoT) {
  int idx = blockIdx.x * 256 + threadIdx.x;
  if (idx < 3 * 512 * 128) {
    int l = idx >> 16, rem = idx & 65535;
    int c = rem >> 7, k = rem & 127;
    int h = c >> 7, o = c & 127;
    WT[idx] = f2h(W[(((l * 4 + h) * 128 + k) << 7) + o]);
  } else {
    int j = idx - 3 * 512 * 128;
    int l = j >> 16, rem = j & 65535;
    int d = rem >> 9, c = rem & 511;
    WoT[j] = f2h(Wo[((l * 512 + c) << 7) + d]);
  }
}

// ---------------- input projection ----------------
__global__ __launch_bounds__(256) void k_inproj(const float* __restrict__ nf,
                                                const float* __restrict__ Wp,
                                                const float* __restrict__ bp,
                                                short* __restrict__ xh) {
  int idx = blockIdx.x * 256 + threadIdx.x;
  int bn = idx >> 7, d = idx & 127;
  float acc = bp[d];
  const float* nr = nf + bn * 7;
#pragma unroll
  for (int i = 0; i < 7; ++i) acc += nr[i] * Wp[(i << 7) + d];
  xh[idx] = f2h(acc);
}

// ---------------- head projection: hT[bh][d][n] = (x @ W[h])^T ----------------
__global__ __launch_bounds__(256) void k_gemm_h(const short* __restrict__ xh,
                                                const short* __restrict__ WT,
                                                short* __restrict__ hT) {
  __shared__ __align__(16) short As[128 * LDP];
  __shared__ __align__(16) short Bs[128 * LDP];
  const int t = threadIdx.x;
  const int bn0 = blockIdx.x << 7;
  const int head = blockIdx.y;
  const int c0 = head << 7;
  const int w = t >> 6, lane = t & 63, lr = lane & 15, lq = lane >> 4;
  const int wr = w >> 1, wc = w & 1;
  f32x4 acc[4][4] = {};
  for (int k0 = 0; k0 < 128; k0 += 64) {
    const int row = t >> 1, half = (t & 1) << 5;
    {
      const short* sa = xh + ((bn0 + row) << 7) + k0 + half;
      short* da = As + row * LDP + half;
      *(short8*)(da) = *(const short8*)(sa);
      *(short8*)(da + 8) = *(const short8*)(sa + 8);
      *(short8*)(da + 16) = *(const short8*)(sa + 16);
      *(short8*)(da + 24) = *(const short8*)(sa + 24);
      const short* sb = WT + ((c0 + row) << 7) + k0 + half;
      short* db = Bs + row * LDP + half;
      *(short8*)(db) = *(const short8*)(sb);
      *(short8*)(db + 8) = *(const short8*)(sb + 8);
      *(short8*)(db + 16) = *(const short8*)(sb + 16);
      *(short8*)(db + 24) = *(const short8*)(sb + 24);
    }
    __syncthreads();
#pragma unroll
    for (int kk = 0; kk < 2; ++kk) {
      f16x8 a[4], b[4];
#pragma unroll
      for (int m = 0; m < 4; ++m)
        a[m] = *(const f16x8*)(As + (wr * 64 + m * 16 + lr) * LDP + (kk << 5) + (lq << 3));
#pragma unroll
      for (int n = 0; n < 4; ++n)
        b[n] = *(const f16x8*)(Bs + (wc * 64 + n * 16 + lr) * LDP + (kk << 5) + (lq << 3));
#pragma unroll
      for (int m = 0; m < 4; ++m)
#pragma unroll
        for (int n = 0; n < 4; ++n)
          acc[m][n] = __builtin_amdgcn_mfma_f32_16x16x32_f16(a[m], b[n], acc[m][n], 0, 0, 0);
    }
    __syncthreads();
  }
  const int b = bn0 >> 10;
  const int nb = bn0 & 1023;
#pragma unroll
  for (int m = 0; m < 4; ++m) {
    int nrow = nb + wr * 64 + m * 16 + (lq << 2);
#pragma unroll
    for (int n = 0; n < 4; ++n) {
      int d = wc * 64 + n * 16 + lr;
      long base = ((long)((((b << 2) + head) << 7) + d) << 10) + nrow;
      short4v v;
      v[0] = f2h(acc[m][n][0]); v[1] = f2h(acc[m][n][1]);
      v[2] = f2h(acc[m][n][2]); v[3] = f2h(acc[m][n][3]);
      *(short4v*)(hT + base) = v;
    }
  }
}

// ---------------- scores: s1, E=exp(s2-max), F=exp(0.2(s2-max)), s2max ----------------
__global__ __launch_bounds__(256) void k_scores(const short* __restrict__ hT,
                                                const float* __restrict__ a1,
                                                const float* __restrict__ a2,
                                                float* __restrict__ s1,
                                                float* __restrict__ e2,
                                                float* __restrict__ f2,
                                                float* __restrict__ s2max) {
  const int bh = blockIdx.x, h = bh & 3;
  __shared__ float a1s[128], a2s[128], red[4];
  const int t = threadIdx.x;
  if (t < 128) a1s[t] = a1[(h << 7) + t];
  else a2s[t - 128] = a2[(h << 7) + t - 128];
  __syncthreads();
  const int n0 = t << 2;
  float ac1[4] = {}, ac2[4] = {};
  const short* hp = hT + ((long)bh << 17) + n0;
  for (int d = 0; d < 128; ++d) {
    short4v hv = *(const short4v*)(hp + ((long)d << 10));
    float w1 = a1s[d], w2 = a2s[d];
#pragma unroll
    for (int q = 0; q < 4; ++q) {
      float f = h2f(hv[q]);
      ac1[q] += f * w1;
      ac2[q] += f * w2;
    }
  }
  f32x4 v1 = {ac1[0], ac1[1], ac1[2], ac1[3]};
  *(f32x4*)(s1 + (bh << 10) + n0) = v1;
  float mx = fmaxf(fmaxf(ac2[0], ac2[1]), fmaxf(ac2[2], ac2[3]));
#pragma unroll
  for (int off = 1; off < 64; off <<= 1) mx = fmaxf(mx, __shfl_xor(mx, off));
  if ((t & 63) == 0) red[t >> 6] = mx;
  __syncthreads();
  const float smax = fmaxf(fmaxf(red[0], red[1]), fmaxf(red[2], red[3]));
  if (t == 0) s2max[bh] = smax;
  f32x4 ev, fv;
#pragma unroll
  for (int q = 0; q < 4; ++q) {
    ev[q] = __expf(ac2[q] - smax);
    fv[q] = __expf(0.2f * (ac2[q] - smax));
  }
  *(f32x4*)(e2 + (bh << 10) + n0) = ev;
  *(f32x4*)(f2 + (bh << 10) + n0) = fv;
}

// ---------------- attention ----------------
// grid (64 bh, 8 it). Each wave owns a 32-row strip (m=2) x full 128 d (n=8).
// P generated directly into MFMA A-fragments: p = max(A_i*E_j, B_i*F_j)
// (== exp(lrelu(s1_i+s2_j)-mi) since exp(max(x,.2x)) = max(exp x, exp .2x)).
// No P LDS round-trip; Hs double-buffered via global_load_lds (swizzled src).
__global__ __launch_bounds__(256) void k_attn(const short* __restrict__ hT,
                                              const float* __restrict__ s1,
                                              const float* __restrict__ e2,
                                              const float* __restrict__ f2,
                                              const float* __restrict__ s2max,
                                              short* __restrict__ attn) {
  __shared__ __align__(16) short Hs[2][128 * LDH];
  __shared__ __align__(16) float Es[1024];
  __shared__ __align__(16) float Fs[1024];
  const int bh = blockIdx.x, it = blockIdx.y;
  const int i0 = it << 7;
  const int t = threadIdx.x;
  const int w = t >> 6, lane = t & 63, lr = lane & 15, lq = lane >> 4;

  const short* hTb = hT + ((long)bh << 17);
  // glds: lane covers d-row grow (+8 per instr); 16B j-chunk pre-swizzled so
  // LDS stays linear while reads use slot = chunk ^ (d&7)  (both-sides rule)
  const int grow = (w << 5) + (lane >> 3);
  const int gcol = ((lane & 7) ^ (lane >> 3)) << 3;
  const short* gsrc = hTb + ((long)grow << 10) + gcol;

#define STAGE(buf, J0)                                              \
  do {                                                              \
    short* ldsb = &Hs[buf][(w << 5) * LDH];                         \
    _Pragma("unroll") for (int i_ = 0; i_ < 4; ++i_)                \
        GLDS16(gsrc + ((long)(i_ << 3) << 10) + (J0),               \
               ldsb + i_ * 8 * LDH);                                \
  } while (0)

  STAGE(0, 0);
  // stage E/F into LDS (read once per block)
  *(f32x4*)&Es[t << 2] = *(const f32x4*)(e2 + (bh << 10) + (t << 2));
  *(f32x4*)&Fs[t << 2] = *(const f32x4*)(f2 + (bh << 10) + (t << 2));

  const float smax = s2max[bh];
  float Ai[2], Bi[2], dsum[2] = {0.f, 0.f};
  int kkd[2], lqd[2], edv[2];
#pragma unroll
  for (int m = 0; m < 2; ++m) {
    int r = (w << 5) + (m << 4) + lr;           // row within block (0..127)
    float s1v = s1[(bh << 10) + i0 + r];
    float x = s1v + smax;
    float mi = fmaxf(x, 0.2f * x);              // upper bound of row max
    Ai[m] = __expf(x - mi);                     // <= 1
    Bi[m] = __expf(0.2f * x - mi);              // <= 1
    int jj = r & 63;                            // diag j within its tile
    kkd[m] = jj >> 5; lqd[m] = (jj >> 3) & 3; edv[m] = jj & 7;
  }
  const int jtd = (i0 + (w << 5)) >> 6;         // wave-uniform diag tile
  f32x4 acc[2][8] = {};
  __syncthreads();

#define TILE(buf, jt, DIAG)                                                   \
  do {                                                                        \
    _Pragma("unroll") for (int kk = 0; kk < 2; ++kk) {                        \
      const int ebase = ((jt) << 6) + (kk << 5) + (lq << 3);                  \
      f32x4 e0 = *(const f32x4*)&Es[ebase];                                   \
      f32x4 e1 = *(const f32x4*)&Es[ebase + 4];                               \
      f32x4 f0 = *(const f32x4*)&Fs[ebase];                                   \
      f32x4 f1 = *(const f32x4*)&Fs[ebase + 4];                               \
      f16x8 af[2];                                                            \
      _Pragma("unroll") for (int m = 0; m < 2; ++m) {                         \
        const bool hit = (DIAG) && (kk == kkd[m]) && (lq == lqd[m]);          \
        _Pragma("unroll") for (int e = 0; e < 8; ++e) {                       \
          float ev_ = e < 4 ? e0[e] : e1[e - 4];                              \
          float fv_ = e < 4 ? f0[e] : f1[e - 4];                              \
          float p = fmaxf(Ai[m] * ev_, Bi[m] * fv_);                          \
          if (hit && e == edv[m]) p = 0.f;                                    \
          dsum[m] += p;                                                       \
          af[m][e] = (_Float16)p;                                             \
        }                                                                     \
      }                                                                       \
      f16x8 bf[8];                                                            \
      _Pragma("unroll") for (int n = 0; n < 8; ++n) {                         \
        const int r_ = (n << 4) + lr;                                         \
        const int slot_ = ((kk << 2) + lq) ^ (r_ & 7);                        \
        bf[n] = *(const f16x8*)(&Hs[buf][r_ * LDH + (slot_ << 3)]);           \
      }                                                                       \
      _Pragma("unroll") for (int m = 0; m < 2; ++m)                           \
        _Pragma("unroll") for (int n = 0; n < 8; ++n)                         \
            acc[m][n] = __builtin_amdgcn_mfma_f32_16x16x32_f16(               \
                af[m], bf[n], acc[m][n], 0, 0, 0);                            \
    }                                                                         \
  } while (0)

#pragma unroll 1
  for (int jt2 = 0; jt2 < 8; ++jt2) {
    const int jA = jt2 << 1, jB = jA + 1;
    STAGE(1, jB << 6);
    __builtin_amdgcn_s_setprio(1);
    if (jtd == jA) TILE(0, jA, 1); else TILE(0, jA, 0);
    __builtin_amdgcn_s_setprio(0);
    __syncthreads();
    if (jt2 < 7) STAGE(0, (jB + 1) << 6);
    __builtin_amdgcn_s_setprio(1);
    if (jtd == jB) TILE(1, jB, 1); else TILE(1, jB, 0);
    __builtin_amdgcn_s_setprio(0);
    __syncthreads();
  }

  const int b = bh >> 2, head = bh & 3;
#pragma unroll
  for (int m = 0; m < 2; ++m) {
    float s = dsum[m];
    s += __shfl_xor(s, 16);
    s += __shfl_xor(s, 32);                     // all lq lanes hold row sum
    float rs = 1.f / s;
    f32x4 d4;
#pragma unroll
    for (int q = 0; q < 4; ++q)
      d4[q] = __shfl(rs, (lane & 48) | ((lq << 2) + q));
    int irow = i0 + (w << 5) + (m << 4) + (lq << 2);
#pragma unroll
    for (int n = 0; n < 8; ++n) {
      int d = (n << 4) + lr;
      long base = ((long)((b << 10) + irow) << 9) + (head << 7) + d;
      attn[base] = f2h(acc[m][n][0] * d4[0]);
      attn[base + 512] = f2h(acc[m][n][1] * d4[1]);
      attn[base + 1024] = f2h(acc[m][n][2] * d4[2]);
      attn[base + 1536] = f2h(acc[m][n][3] * d4[3]);
    }
  }
#undef STAGE
#undef TILE
}

// ---------------- out-proj + bias (+residual) + LN (+relu) ----------------
template <int HAS_RES, int DO_RELU, int WRITE_OUT>
__global__ __launch_bounds__(256) void k_outproj(const short* __restrict__ attn,
                                                 const short* __restrict__ WoT,
                                                 const float* __restrict__ bo,
                                                 const float* __restrict__ gamma,
                                                 const float* __restrict__ beta,
                                                 float* __restrict__ xf,
                                                 short* __restrict__ xh,
                                                 float* __restrict__ outp) {
  __shared__ __align__(16) short As[64 * LDP];
  __shared__ __align__(16) short Bs[128 * LDP];
  const int t = threadIdx.x;
  const int bn0 = blockIdx.x << 6;
  const int w = t >> 6, lane = t & 63, lr = lane & 15, lq = lane >> 4;
  f32x4 acc[8] = {};
  const int rowA = t >> 2, chA = (t & 3) << 4;
  const int rowB = t >> 1, chB = (t & 1) << 5;
  for (int k0 = 0; k0 < 512; k0 += 64) {
    {
      const short* sa = attn + ((long)(bn0 + rowA) << 9) + k0 + chA;
      short* da = As + rowA * LDP + chA;
      *(short8*)(da) = *(const short8*)(sa);
      *(short8*)(da + 8) = *(const short8*)(sa + 8);
      const short* sb = WoT + (rowB << 9) + k0 + chB;
      short* db = Bs + rowB * LDP + chB;
      *(short8*)(db) = *(const short8*)(sb);
      *(short8*)(db + 8) = *(const short8*)(sb + 8);
      *(short8*)(db + 16) = *(const short8*)(sb + 16);
      *(short8*)(db + 24) = *(const short8*)(sb + 24);
    }
    __syncthreads();
#pragma unroll
    for (int kk = 0; kk < 2; ++kk) {
      f16x8 a = *(const f16x8*)(As + ((w << 4) + lr) * LDP + (kk << 5) + (lq << 3));
#pragma unroll
      for (int n = 0; n < 8; ++n) {
        f16x8 b = *(const f16x8*)(Bs + ((n << 4) + lr) * LDP + (kk << 5) + (lq << 3));
        acc[n] = __builtin_amdgcn_mfma_f32_16x16x32_f16(a, b, acc[n], 0, 0, 0);
      }
    }
    __syncthreads();
  }
  float v[8][4], gam[8], bet[8];
#pragma unroll
  for (int n = 0; n < 8; ++n) {
    int d = (n << 4) + lr;
    float bv = bo[d];
    gam[n] = gamma[d];
    bet[n] = beta[d];
#pragma unroll
    for (int r = 0; r < 4; ++r) {
      float x = acc[n][r] + bv;
      if (HAS_RES) x += xf[((bn0 + (w << 4) + (lq << 2) + r) << 7) + d];
      v[n][r] = x;
    }
  }
#pragma unroll
  for (int r = 0; r < 4; ++r) {
    float s = 0.f, q = 0.f;
#pragma unroll
    for (int n = 0; n < 8; ++n) { s += v[n][r]; q += v[n][r] * v[n][r]; }
#pragma unroll
    for (int mk = 1; mk < 16; mk <<= 1) { s += __shfl_xor(s, mk); q += __shfl_xor(q, mk); }
    float mean = s * 0.0078125f;
    float var = q * 0.0078125f - mean * mean;
    float rstd = rsqrtf(var + 1e-5f);
    int row = bn0 + (w << 4) + (lq << 2) + r;
#pragma unroll
    for (int n = 0; n < 8; ++n) {
      int d = (n << 4) + lr;
      float o = (v[n][r] - mean) * rstd * gam[n] + bet[n];
      if (DO_RELU) o = fmaxf(o, 0.f);
      if (WRITE_OUT) {
        outp[(row << 7) + d] = o;
      } else {
        xh[(row << 7) + d] = f2h(o);
        xf[(row << 7) + d] = o;
      }
    }
  }
}

extern "C" void kernel_launch(void* const* d_in, const int* in_sizes, int n_in,
                              void* d_out, int out_size, void* d_ws, size_t ws_size,
                              hipStream_t stream) {
  const float* nf = (const float*)d_in[0];
  const float* Wp = (const float*)d_in[1];
  const float* bp = (const float*)d_in[2];
  const float* W = (const float*)d_in[3];
  const float* a1 = (const float*)d_in[4];
  const float* a2 = (const float*)d_in[5];
  const float* Wo = (const float*)d_in[6];
  const float* bo = (const float*)d_in[7];
  const float* gamma = (const float*)d_in[8];
  const float* beta = (const float*)d_in[9];
  float* outp = (float*)d_out;

  char* ws = (char*)d_ws;
  short* xh = (short*)(ws);                           // 4 MB
  float* xf = (float*)(ws + (4ll << 20));             // 8 MB
  short* hT = (short*)(ws + (12ll << 20));            // 16 MB
  short* attn = (short*)(ws + (28ll << 20));          // 16 MB
  float* s1 = (float*)(ws + (44ll << 20));            // 256 KB
  float* e2 = (float*)(ws + (44ll << 20) + 262144);   // 256 KB
  float* f2 = (float*)(ws + (44ll << 20) + 524288);   // 256 KB
  float* s2m = (float*)(ws + (44ll << 20) + 786432);  // 256 B
  short* WT = (short*)(ws + (45ll << 20));            // 384 KB
  short* WoT = (short*)(ws + (45ll << 20) + 393216);  // 384 KB

  k_tw<<<1536, 256, 0, stream>>>(W, Wo, WT, WoT);
  k_inproj<<<8192, 256, 0, stream>>>(nf, Wp, bp, xh);
  for (int l = 0; l < 3; ++l) {
    k_gemm_h<<<dim3(128, 4), 256, 0, stream>>>(xh, WT + l * 65536, hT);
    k_scores<<<64, 256, 0, stream>>>(hT, a1 + l * 512, a2 + l * 512, s1, e2, f2, s2m);
    k_attn<<<dim3(64, 8), 256, 0, stream>>>(hT, s1, e2, f2, s2m, attn);
    if (l == 0)
      k_outproj<0, 1, 0><<<256, 256, 0, stream>>>(attn, WoT + l * 65536, bo + l * 128,
                                                  gamma + l * 128, beta + l * 128, xf, xh, outp);
    else if (l == 1)
      k_outproj<1, 1, 0><<<256, 256, 0, stream>>>(attn, WoT + l * 65536, bo + l * 128,
                                                  gamma + l * 128, beta + l * 128, xf, xh, outp);
    else
      k_outproj<1, 0, 1><<<256, 256, 0, stream>>>(attn, WoT + l * 65536, bo + l * 128,
                                                  gamma + l * 128, beta + l * 128, xf, xh, outp);
  }
}

// Round 5
// 183.099 us; speedup vs baseline: 1.3601x; 1.0099x over previous
//
#include <hip/hip_runtime.h>
#include <hip/hip_bf16.h>

typedef __attribute__((ext_vector_type(8))) _Float16 f16x8;
typedef __attribute__((ext_vector_type(2))) _Float16 f16x2;
typedef __attribute__((ext_vector_type(8))) short short8;
typedef __attribute__((ext_vector_type(4))) short short4v;
typedef __attribute__((ext_vector_type(4))) float f32x4;

#define LDP 72   // LDS row stride (shorts) for reg-staged GEMM tiles
#define LDH 64   // Hs row stride (shorts): linear (global_load_lds dest)

typedef const __attribute__((address_space(1))) unsigned int* gas_ptr;
typedef __attribute__((address_space(3))) unsigned int* las_ptr;
#define GLDS16(gp, lp) \
  __builtin_amdgcn_global_load_lds((gas_ptr)(gp), (las_ptr)(lp), 16, 0, 0)

#if __has_builtin(__builtin_amdgcn_fdot2)
#define FDOT2(a, b, c) __builtin_amdgcn_fdot2((a), (b), (c), false)
#else
__device__ __forceinline__ float FDOT2(f16x2 a, f16x2 b, float c) {
  return c + (float)a[0] * (float)b[0] + (float)a[1] * (float)b[1];
}
#endif

union h8u {
  f16x8 v;
  f16x2 h[4];
};

__device__ __forceinline__ short f2h(float f) {
  union { _Float16 h; short s; } u; u.h = (_Float16)f; return u.s;
}
__device__ __forceinline__ float h2f(short s) {
  union { short s; _Float16 h; } u; u.s = s; return (float)u.h;
}

// ---------------- weight transpose + f32->f16 ----------------
__global__ __launch_bounds__(256) void k_tw(const float* __restrict__ W,
                                            const float* __restrict__ Wo,
                                            short* __restrict__ WT,
                                            short* __restrict__ WoT) {
  int idx = blockIdx.x * 256 + threadIdx.x;
  if (idx < 3 * 512 * 128) {
    int l = idx >> 16, rem = idx & 65535;
    int c = rem >> 7, k = rem & 127;
    int h = c >> 7, o = c & 127;
    WT[idx] = f2h(W[(((l * 4 + h) * 128 + k) << 7) + o]);
  } else {
    int j = idx - 3 * 512 * 128;
    int l = j >> 16, rem = j & 65535;
    int d = rem >> 9, c = rem & 511;
    WoT[j] = f2h(Wo[((l * 512 + c) << 7) + d]);
  }
}

// ---------------- input projection ----------------
__global__ __launch_bounds__(256) void k_inproj(const float* __restrict__ nf,
                                                const float* __restrict__ Wp,
                                                const float* __restrict__ bp,
                                                short* __restrict__ xh) {
  int idx = blockIdx.x * 256 + threadIdx.x;
  int bn = idx >> 7, d = idx & 127;
  float acc = bp[d];
  const float* nr = nf + bn * 7;
#pragma unroll
  for (int i = 0; i < 7; ++i) acc += nr[i] * Wp[(i << 7) + d];
  xh[idx] = f2h(acc);
}

// ---------------- head projection + fused s1/s2 ----------------
// hT[bh][d][n] = (x @ W[h])^T ; s1/s2[bh][n] = h·a1 / h·a2 (exact f32)
__global__ __launch_bounds__(256) void k_gemm_h(const short* __restrict__ xh,
                                                const short* __restrict__ WT,
                                                short* __restrict__ hT,
                                                const float* __restrict__ a1,
                                                const float* __restrict__ a2,
                                                float* __restrict__ s1g,
                                                float* __restrict__ s2g) {
  __shared__ __align__(16) short As[128 * LDP];
  __shared__ __align__(16) short Bs[128 * LDP];
  __shared__ float sred[2][2][128];
  const int t = threadIdx.x;
  const int bn0 = blockIdx.x << 7;
  const int head = blockIdx.y;
  const int c0 = head << 7;
  const int w = t >> 6, lane = t & 63, lr = lane & 15, lq = lane >> 4;
  const int wr = w >> 1, wc = w & 1;
  f32x4 acc[4][4] = {};
  for (int k0 = 0; k0 < 128; k0 += 64) {
    const int row = t >> 1, half = (t & 1) << 5;
    {
      const short* sa = xh + ((bn0 + row) << 7) + k0 + half;
      short* da = As + row * LDP + half;
      *(short8*)(da) = *(const short8*)(sa);
      *(short8*)(da + 8) = *(const short8*)(sa + 8);
      *(short8*)(da + 16) = *(const short8*)(sa + 16);
      *(short8*)(da + 24) = *(const short8*)(sa + 24);
      const short* sb = WT + ((c0 + row) << 7) + k0 + half;
      short* db = Bs + row * LDP + half;
      *(short8*)(db) = *(const short8*)(sb);
      *(short8*)(db + 8) = *(const short8*)(sb + 8);
      *(short8*)(db + 16) = *(const short8*)(sb + 16);
      *(short8*)(db + 24) = *(const short8*)(sb + 24);
    }
    __syncthreads();
#pragma unroll
    for (int kk = 0; kk < 2; ++kk) {
      f16x8 a[4], b[4];
#pragma unroll
      for (int m = 0; m < 4; ++m)
        a[m] = *(const f16x8*)(As + (wr * 64 + m * 16 + lr) * LDP + (kk << 5) + (lq << 3));
#pragma unroll
      for (int n = 0; n < 4; ++n)
        b[n] = *(const f16x8*)(Bs + (wc * 64 + n * 16 + lr) * LDP + (kk << 5) + (lq << 3));
#pragma unroll
      for (int m = 0; m < 4; ++m)
#pragma unroll
        for (int n = 0; n < 4; ++n)
          acc[m][n] = __builtin_amdgcn_mfma_f32_16x16x32_f16(a[m], b[n], acc[m][n], 0, 0, 0);
    }
    __syncthreads();
  }
  const int b = bn0 >> 10;
  const int nb = bn0 & 1023;
  // fused s1/s2: per-row dot with a1/a2 over this block's full 128-d tile
  float a1v[4], a2v[4];
#pragma unroll
  for (int n = 0; n < 4; ++n) {
    int d = wc * 64 + n * 16 + lr;
    a1v[n] = a1[(head << 7) + d];
    a2v[n] = a2[(head << 7) + d];
  }
#pragma unroll
  for (int m = 0; m < 4; ++m)
#pragma unroll
    for (int r = 0; r < 4; ++r) {
      float v1 = 0.f, v2 = 0.f;
#pragma unroll
      for (int n = 0; n < 4; ++n) {
        v1 += acc[m][n][r] * a1v[n];
        v2 += acc[m][n][r] * a2v[n];
      }
#pragma unroll
      for (int off = 1; off < 16; off <<= 1) {
        v1 += __shfl_xor(v1, off);
        v2 += __shfl_xor(v2, off);
      }
      if (lr == 0) {
        int row = wr * 64 + m * 16 + (lq << 2) + r;
        sred[wc][0][row] = v1;
        sred[wc][1][row] = v2;
      }
    }
#pragma unroll
  for (int m = 0; m < 4; ++m) {
    int nrow = nb + wr * 64 + m * 16 + (lq << 2);
#pragma unroll
    for (int n = 0; n < 4; ++n) {
      int d = wc * 64 + n * 16 + lr;
      long base = ((long)((((b << 2) + head) << 7) + d) << 10) + nrow;
      short4v v;
      v[0] = f2h(acc[m][n][0]); v[1] = f2h(acc[m][n][1]);
      v[2] = f2h(acc[m][n][2]); v[3] = f2h(acc[m][n][3]);
      *(short4v*)(hT + base) = v;
    }
  }
  __syncthreads();
  {
    const int bh_ = (b << 2) + head;
    if (t < 128)
      s1g[(bh_ << 10) + nb + t] = sred[0][0][t] + sred[1][0][t];
    else
      s2g[(bh_ << 10) + nb + (t - 128)] = sred[0][1][t - 128] + sred[1][1][t - 128];
  }
}

// ---------------- tiny: s2 -> max, E=exp(s2-max) f16, F=exp(.2(s2-max)) f16 ----
__global__ __launch_bounds__(256) void k_ef(const float* __restrict__ s2g,
                                            float* __restrict__ s2m,
                                            short* __restrict__ Eh,
                                            short* __restrict__ Fh) {
  const int bh = blockIdx.x, t = threadIdx.x;
  __shared__ float red[4];
  f32x4 v = *(const f32x4*)&s2g[(bh << 10) + (t << 2)];
  float mx = fmaxf(fmaxf(v[0], v[1]), fmaxf(v[2], v[3]));
#pragma unroll
  for (int off = 1; off < 64; off <<= 1) mx = fmaxf(mx, __shfl_xor(mx, off));
  if ((t & 63) == 0) red[t >> 6] = mx;
  __syncthreads();
  const float smax = fmaxf(fmaxf(red[0], red[1]), fmaxf(red[2], red[3]));
  if (t == 0) s2m[bh] = smax;
  short4v e, f;
#pragma unroll
  for (int q = 0; q < 4; ++q) {
    e[q] = f2h(__expf(v[q] - smax));
    f[q] = f2h(__expf(0.2f * (v[q] - smax)));
  }
  *(short4v*)&Eh[(bh << 10) + (t << 2)] = e;
  *(short4v*)&Fh[(bh << 10) + (t << 2)] = f;
}

// ---------------- attention ----------------
// grid (64 bh, 4 it). Wave owns 64-row strip (m=4) x full 128 d (n=8).
// P in packed f16 straight into MFMA A-frags: p = pk_max(Ai*E, Bi*F);
// dsum via fdot2 (f32). Diagonal zeroed by per-m static mask in the wave's
// diag tile (kk==m>>1 compile-time). Hs dbuf via global_load_lds, XOR-swizzle.
__global__ __launch_bounds__(256, 1) void k_attn(const short* __restrict__ hT,
                                                 const float* __restrict__ s1,
                                                 const short* __restrict__ Eh,
                                                 const short* __restrict__ Fh,
                                                 const float* __restrict__ s2max,
                                                 short* __restrict__ attn) {
  __shared__ __align__(16) short Hs[2][128 * LDH];
  __shared__ __align__(16) _Float16 Esh[1024];
  __shared__ __align__(16) _Float16 Fsh[1024];
  const int bh = blockIdx.x, it = blockIdx.y;
  const int i0 = it << 8;
  const int t = threadIdx.x;
  const int w = t >> 6, lane = t & 63, lr = lane & 15, lq = lane >> 4;

  const short* hTb = hT + ((long)bh << 17);
  const int grow = (w << 5) + (lane >> 3);
  const int gcol = ((lane & 7) ^ (lane >> 3)) << 3;
  const short* gsrc = hTb + ((long)grow << 10) + gcol;

#define STAGE(buf, J0)                                             \
  do {                                                             \
    short* ldsb = &Hs[buf][(w << 5) << 6];                         \
    _Pragma("unroll") for (int i_ = 0; i_ < 4; ++i_)               \
        GLDS16(gsrc + ((long)(i_ << 3) << 10) + (J0),              \
               ldsb + ((i_ << 3) << 6));                           \
  } while (0)

  STAGE(0, 0);
  *(short4v*)&Esh[t << 2] = *(const short4v*)&Eh[(bh << 10) + (t << 2)];
  *(short4v*)&Fsh[t << 2] = *(const short4v*)&Fh[(bh << 10) + (t << 2)];

  const float smax = s2max[bh];
  f16x8 Ai8[4], Bi8[4];
  const f16x2 one2 = {(_Float16)1.f, (_Float16)1.f};
  f16x8 dmask[4];
  float dsum[4] = {0.f, 0.f, 0.f, 0.f};
#pragma unroll
  for (int m = 0; m < 4; ++m) {
    const int rblk = (w << 6) + (m << 4) + lr;
    float s1v = s1[(bh << 10) + i0 + rblk];
    float x = s1v + smax;
    float mi = fmaxf(x, 0.2f * x);  // upper bound of row max (lrelu monotone)
    _Float16 A_ = (_Float16)__expf(x - mi);
    _Float16 B_ = (_Float16)__expf(0.2f * x - mi);
#pragma unroll
    for (int e = 0; e < 8; ++e) { Ai8[m][e] = A_; Bi8[m][e] = B_; }
    const int lqz = ((m << 1) + (lr >> 3)) & 3, ez = lr & 7;
#pragma unroll
    for (int e = 0; e < 8; ++e)
      dmask[m][e] = (lq == lqz && e == ez) ? (_Float16)0.f : (_Float16)1.f;
  }
  const int jtd = (it << 2) + w;  // wave-uniform diagonal j-tile
  f32x4 acc[4][8] = {};
  __syncthreads();

#define TILE(buf, jt, DIAG)                                                    \
  do {                                                                         \
    _Pragma("unroll") for (int kk = 0; kk < 2; ++kk) {                         \
      const int ebase = ((jt) << 6) + (kk << 5) + (lq << 3);                   \
      f16x8 ev8 = *(const f16x8*)&Esh[ebase];                                  \
      f16x8 fv8 = *(const f16x8*)&Fsh[ebase];                                  \
      f16x8 bf[8];                                                             \
      _Pragma("unroll") for (int n = 0; n < 8; ++n) {                          \
        const int r_ = (n << 4) + lr;                                          \
        const int slot_ = ((kk << 2) + lq) ^ (r_ & 7);                         \
        bf[n] = *(const f16x8*)(&Hs[buf][(r_ << 6) + (slot_ << 3)]);           \
      }                                                                        \
      f16x8 af[4];                                                             \
      _Pragma("unroll") for (int m = 0; m < 4; ++m) {                          \
        f16x8 pm = __builtin_elementwise_max(Ai8[m] * ev8, Bi8[m] * fv8);      \
        if ((DIAG) && kk == (m >> 1)) pm = pm * dmask[m];                      \
        af[m] = pm;                                                            \
        h8u u_; u_.v = pm;                                                     \
        _Pragma("unroll") for (int p = 0; p < 4; ++p)                          \
            dsum[m] = FDOT2(u_.h[p], one2, dsum[m]);                           \
      }                                                                        \
      _Pragma("unroll") for (int m = 0; m < 4; ++m)                            \
        _Pragma("unroll") for (int n = 0; n < 8; ++n)                          \
            acc[m][n] = __builtin_amdgcn_mfma_f32_16x16x32_f16(                \
                af[m], bf[n], acc[m][n], 0, 0, 0);                             \
    }                                                                          \
  } while (0)

#pragma unroll 1
  for (int jt2 = 0; jt2 < 8; ++jt2) {
    const int jA = jt2 << 1, jB = jA | 1;
    STAGE(1, jB << 6);
    __builtin_amdgcn_s_setprio(1);
    TILE(0, jA, jA == jtd);
    __builtin_amdgcn_s_setprio(0);
    __syncthreads();
    if (jt2 < 7) STAGE(0, (jA + 2) << 6);
    __builtin_amdgcn_s_setprio(1);
    TILE(1, jB, jB == jtd);
    __builtin_amdgcn_s_setprio(0);
    __syncthreads();
  }

  const int b = bh >> 2, head = bh & 3;
#pragma unroll
  for (int m = 0; m < 4; ++m) {
    float s = dsum[m];
    s += __shfl_xor(s, 16);
    s += __shfl_xor(s, 32);  // all lq-replica lanes hold the row sum
    float rs = 1.f / s;
    f32x4 d4;
#pragma unroll
    for (int q = 0; q < 4; ++q)
      d4[q] = __shfl(rs, (lane & 48) | ((lq << 2) + q));
    int irow = i0 + (w << 6) + (m << 4) + (lq << 2);
#pragma unroll
    for (int n = 0; n < 8; ++n) {
      int d = (n << 4) + lr;
      long base = ((long)((b << 10) + irow) << 9) + (head << 7) + d;
      attn[base] = f2h(acc[m][n][0] * d4[0]);
      attn[base + 512] = f2h(acc[m][n][1] * d4[1]);
      attn[base + 1024] = f2h(acc[m][n][2] * d4[2]);
      attn[base + 1536] = f2h(acc[m][n][3] * d4[3]);
    }
  }
#undef STAGE
#undef TILE
}

// ---------------- out-proj + bias (+residual) + LN (+relu) ----------------
template <int HAS_RES, int DO_RELU, int WRITE_OUT>
__global__ __launch_bounds__(256) void k_outproj(const short* __restrict__ attn,
                                                 const short* __restrict__ WoT,
                                                 const float* __restrict__ bo,
                                                 const float* __restrict__ gamma,
                                                 const float* __restrict__ beta,
                                                 float* __restrict__ xf,
                                                 short* __restrict__ xh,
                                                 float* __restrict__ outp) {
  __shared__ __align__(16) short As[64 * LDP];
  __shared__ __align__(16) short Bs[128 * LDP];
  const int t = threadIdx.x;
  const int bn0 = blockIdx.x << 6;
  const int w = t >> 6, lane = t & 63, lr = lane & 15, lq = lane >> 4;
  f32x4 acc[8] = {};
  const int rowA = t >> 2, chA = (t & 3) << 4;
  const int rowB = t >> 1, chB = (t & 1) << 5;
  for (int k0 = 0; k0 < 512; k0 += 64) {
    {
      const short* sa = attn + ((long)(bn0 + rowA) << 9) + k0 + chA;
      short* da = As + rowA * LDP + chA;
      *(short8*)(da) = *(const short8*)(sa);
      *(short8*)(da + 8) = *(const short8*)(sa + 8);
      const short* sb = WoT + (rowB << 9) + k0 + chB;
      short* db = Bs + rowB * LDP + chB;
      *(short8*)(db) = *(const short8*)(sb);
      *(short8*)(db + 8) = *(const short8*)(sb + 8);
      *(short8*)(db + 16) = *(const short8*)(sb + 16);
      *(short8*)(db + 24) = *(const short8*)(sb + 24);
    }
    __syncthreads();
#pragma unroll
    for (int kk = 0; kk < 2; ++kk) {
      f16x8 a = *(const f16x8*)(As + ((w << 4) + lr) * LDP + (kk << 5) + (lq << 3));
#pragma unroll
      for (int n = 0; n < 8; ++n) {
        f16x8 b = *(const f16x8*)(Bs + ((n << 4) + lr) * LDP + (kk << 5) + (lq << 3));
        acc[n] = __builtin_amdgcn_mfma_f32_16x16x32_f16(a, b, acc[n], 0, 0, 0);
      }
    }
    __syncthreads();
  }
  float v[8][4], gam[8], bet[8];
#pragma unroll
  for (int n = 0; n < 8; ++n) {
    int d = (n << 4) + lr;
    float bv = bo[d];
    gam[n] = gamma[d];
    bet[n] = beta[d];
#pragma unroll
    for (int r = 0; r < 4; ++r) {
      float x = acc[n][r] + bv;
      if (HAS_RES) x += xf[((bn0 + (w << 4) + (lq << 2) + r) << 7) + d];
      v[n][r] = x;
    }
  }
#pragma unroll
  for (int r = 0; r < 4; ++r) {
    float s = 0.f, q = 0.f;
#pragma unroll
    for (int n = 0; n < 8; ++n) { s += v[n][r]; q += v[n][r] * v[n][r]; }
#pragma unroll
    for (int mk = 1; mk < 16; mk <<= 1) { s += __shfl_xor(s, mk); q += __shfl_xor(q, mk); }
    float mean = s * 0.0078125f;
    float var = q * 0.0078125f - mean * mean;
    float rstd = rsqrtf(var + 1e-5f);
    int row = bn0 + (w << 4) + (lq << 2) + r;
#pragma unroll
    for (int n = 0; n < 8; ++n) {
      int d = (n << 4) + lr;
      float o = (v[n][r] - mean) * rstd * gam[n] + bet[n];
      if (DO_RELU) o = fmaxf(o, 0.f);
      if (WRITE_OUT) {
        outp[(row << 7) + d] = o;
      } else {
        xh[(row << 7) + d] = f2h(o);
        xf[(row << 7) + d] = o;
      }
    }
  }
}

extern "C" void kernel_launch(void* const* d_in, const int* in_sizes, int n_in,
                              void* d_out, int out_size, void* d_ws, size_t ws_size,
                              hipStream_t stream) {
  const float* nf = (const float*)d_in[0];
  const float* Wp = (const float*)d_in[1];
  const float* bp = (const float*)d_in[2];
  const float* W = (const float*)d_in[3];
  const float* a1 = (const float*)d_in[4];
  const float* a2 = (const float*)d_in[5];
  const float* Wo = (const float*)d_in[6];
  const float* bo = (const float*)d_in[7];
  const float* gamma = (const float*)d_in[8];
  const float* beta = (const float*)d_in[9];
  float* outp = (float*)d_out;

  char* ws = (char*)d_ws;
  short* xh = (short*)(ws);                                    // 4 MB
  float* xf = (float*)(ws + (4ll << 20));                      // 8 MB
  short* hT = (short*)(ws + (12ll << 20));                     // 16 MB
  short* attn = (short*)(ws + (28ll << 20));                   // 16 MB
  float* s1 = (float*)(ws + (44ll << 20));                     // 256 KB
  float* s2g = (float*)(ws + (44ll << 20) + (256ll << 10));    // 256 KB
  short* Eh = (short*)(ws + (44ll << 20) + (512ll << 10));     // 128 KB
  short* Fh = (short*)(ws + (44ll << 20) + (640ll << 10));     // 128 KB
  float* s2m = (float*)(ws + (44ll << 20) + (768ll << 10));    // 1 KB
  short* WT = (short*)(ws + (45ll << 20));                     // 384 KB
  short* WoT = (short*)(ws + (45ll << 20) + 393216);           // 384 KB

  k_tw<<<1536, 256, 0, stream>>>(W, Wo, WT, WoT);
  k_inproj<<<8192, 256, 0, stream>>>(nf, Wp, bp, xh);
  for (int l = 0; l < 3; ++l) {
    k_gemm_h<<<dim3(128, 4), 256, 0, stream>>>(xh, WT + l * 65536, hT,
                                               a1 + l * 512, a2 + l * 512, s1, s2g);
    k_ef<<<64, 256, 0, stream>>>(s2g, s2m, Eh, Fh);
    k_attn<<<dim3(64, 4), 256, 0, stream>>>(hT, s1, Eh, Fh, s2m, attn);
    if (l == 0)
      k_outproj<0, 1, 0><<<256, 256, 0, stream>>>(attn, WoT + l * 65536, bo + l * 128,
                                                  gamma + l * 128, beta + l * 128, xf, xh, outp);
    else if (l == 1)
      k_outproj<1, 1, 0><<<256, 256, 0, stream>>>(attn, WoT + l * 65536, bo + l * 128,
                                                  gamma + l * 128, beta + l * 128, xf, xh, outp);
    else
      k_outproj<1, 0, 1><<<256, 256, 0, stream>>>(attn, WoT + l * 65536, bo + l * 128,
                                                  gamma + l * 128, beta + l * 128, xf, xh, outp);
  }
}

// Round 6
// 170.784 us; speedup vs baseline: 1.4582x; 1.0721x over previous
//
#include <hip/hip_runtime.h>
#include <hip/hip_bf16.h>

typedef __attribute__((ext_vector_type(8))) _Float16 f16x8;
typedef __attribute__((ext_vector_type(2))) _Float16 f16x2;
typedef __attribute__((ext_vector_type(8))) short short8;
typedef __attribute__((ext_vector_type(4))) short short4v;
typedef __attribute__((ext_vector_type(4))) float f32x4;

#define LDP 72   // LDS row stride (shorts) for reg-staged GEMM tiles
#define LDH 64   // Hs row stride (shorts): linear (global_load_lds dest)

typedef const __attribute__((address_space(1))) unsigned int* gas_ptr;
typedef __attribute__((address_space(3))) unsigned int* las_ptr;
#define GLDS16(gp, lp) \
  __builtin_amdgcn_global_load_lds((gas_ptr)(gp), (las_ptr)(lp), 16, 0, 0)

#if __has_builtin(__builtin_amdgcn_fdot2)
#define FDOT2(a, b, c) __builtin_amdgcn_fdot2((a), (b), (c), false)
#else
__device__ __forceinline__ float FDOT2(f16x2 a, f16x2 b, float c) {
  return c + (float)a[0] * (float)b[0] + (float)a[1] * (float)b[1];
}
#endif

union h8u {
  f16x8 v;
  f16x2 h[4];
};

__device__ __forceinline__ short f2h(float f) {
  union { _Float16 h; short s; } u; u.h = (_Float16)f; return u.s;
}
__device__ __forceinline__ float h2f(short s) {
  union { short s; _Float16 h; } u; u.s = s; return (float)u.h;
}

// ---------------- weight transpose + f32->f16 ----------------
__global__ __launch_bounds__(256) void k_tw(const float* __restrict__ W,
                                            const float* __restrict__ Wo,
                                            short* __restrict__ WT,
                                            short* __restrict__ WoT) {
  int idx = blockIdx.x * 256 + threadIdx.x;
  if (idx < 3 * 512 * 128) {
    int l = idx >> 16, rem = idx & 65535;
    int c = rem >> 7, k = rem & 127;
    int h = c >> 7, o = c & 127;
    WT[idx] = f2h(W[(((l * 4 + h) * 128 + k) << 7) + o]);
  } else {
    int j = idx - 3 * 512 * 128;
    int l = j >> 16, rem = j & 65535;
    int d = rem >> 9, c = rem & 511;
    WoT[j] = f2h(Wo[((l * 512 + c) << 7) + d]);
  }
}

// ---------------- input projection ----------------
__global__ __launch_bounds__(256) void k_inproj(const float* __restrict__ nf,
                                                const float* __restrict__ Wp,
                                                const float* __restrict__ bp,
                                                short* __restrict__ xh) {
  int idx = blockIdx.x * 256 + threadIdx.x;
  int bn = idx >> 7, d = idx & 127;
  float acc = bp[d];
  const float* nr = nf + bn * 7;
#pragma unroll
  for (int i = 0; i < 7; ++i) acc += nr[i] * Wp[(i << 7) + d];
  xh[idx] = f2h(acc);
}

// ---------------- head projection + fused s1/s2 ----------------
// hT[bh][d][n] = (x @ W[h])^T ; s1/s2[bh][n] = h·a1 / h·a2 (exact f32)
__global__ __launch_bounds__(256) void k_gemm_h(const short* __restrict__ xh,
                                                const short* __restrict__ WT,
                                                short* __restrict__ hT,
                                                const float* __restrict__ a1,
                                                const float* __restrict__ a2,
                                                float* __restrict__ s1g,
                                                float* __restrict__ s2g) {
  __shared__ __align__(16) short As[128 * LDP];
  __shared__ __align__(16) short Bs[128 * LDP];
  __shared__ float sred[2][2][128];
  const int t = threadIdx.x;
  const int bn0 = blockIdx.x << 7;
  const int head = blockIdx.y;
  const int c0 = head << 7;
  const int w = t >> 6, lane = t & 63, lr = lane & 15, lq = lane >> 4;
  const int wr = w >> 1, wc = w & 1;
  f32x4 acc[4][4] = {};
  for (int k0 = 0; k0 < 128; k0 += 64) {
    const int row = t >> 1, half = (t & 1) << 5;
    {
      const short* sa = xh + ((bn0 + row) << 7) + k0 + half;
      short* da = As + row * LDP + half;
      *(short8*)(da) = *(const short8*)(sa);
      *(short8*)(da + 8) = *(const short8*)(sa + 8);
      *(short8*)(da + 16) = *(const short8*)(sa + 16);
      *(short8*)(da + 24) = *(const short8*)(sa + 24);
      const short* sb = WT + ((c0 + row) << 7) + k0 + half;
      short* db = Bs + row * LDP + half;
      *(short8*)(db) = *(const short8*)(sb);
      *(short8*)(db + 8) = *(const short8*)(sb + 8);
      *(short8*)(db + 16) = *(const short8*)(sb + 16);
      *(short8*)(db + 24) = *(const short8*)(sb + 24);
    }
    __syncthreads();
#pragma unroll
    for (int kk = 0; kk < 2; ++kk) {
      f16x8 a[4], b[4];
#pragma unroll
      for (int m = 0; m < 4; ++m)
        a[m] = *(const f16x8*)(As + (wr * 64 + m * 16 + lr) * LDP + (kk << 5) + (lq << 3));
#pragma unroll
      for (int n = 0; n < 4; ++n)
        b[n] = *(const f16x8*)(Bs + (wc * 64 + n * 16 + lr) * LDP + (kk << 5) + (lq << 3));
#pragma unroll
      for (int m = 0; m < 4; ++m)
#pragma unroll
        for (int n = 0; n < 4; ++n)
          acc[m][n] = __builtin_amdgcn_mfma_f32_16x16x32_f16(a[m], b[n], acc[m][n], 0, 0, 0);
    }
    __syncthreads();
  }
  const int b = bn0 >> 10;
  const int nb = bn0 & 1023;
  // fused s1/s2: per-row dot with a1/a2 over this block's full 128-d tile
  float a1v[4], a2v[4];
#pragma unroll
  for (int n = 0; n < 4; ++n) {
    int d = wc * 64 + n * 16 + lr;
    a1v[n] = a1[(head << 7) + d];
    a2v[n] = a2[(head << 7) + d];
  }
#pragma unroll
  for (int m = 0; m < 4; ++m)
#pragma unroll
    for (int r = 0; r < 4; ++r) {
      float v1 = 0.f, v2 = 0.f;
#pragma unroll
      for (int n = 0; n < 4; ++n) {
        v1 += acc[m][n][r] * a1v[n];
        v2 += acc[m][n][r] * a2v[n];
      }
#pragma unroll
      for (int off = 1; off < 16; off <<= 1) {
        v1 += __shfl_xor(v1, off);
        v2 += __shfl_xor(v2, off);
      }
      if (lr == 0) {
        int row = wr * 64 + m * 16 + (lq << 2) + r;
        sred[wc][0][row] = v1;
        sred[wc][1][row] = v2;
      }
    }
#pragma unroll
  for (int m = 0; m < 4; ++m) {
    int nrow = nb + wr * 64 + m * 16 + (lq << 2);
#pragma unroll
    for (int n = 0; n < 4; ++n) {
      int d = wc * 64 + n * 16 + lr;
      long base = ((long)((((b << 2) + head) << 7) + d) << 10) + nrow;
      short4v v;
      v[0] = f2h(acc[m][n][0]); v[1] = f2h(acc[m][n][1]);
      v[2] = f2h(acc[m][n][2]); v[3] = f2h(acc[m][n][3]);
      *(short4v*)(hT + base) = v;
    }
  }
  __syncthreads();
  {
    const int bh_ = (b << 2) + head;
    if (t < 128)
      s1g[(bh_ << 10) + nb + t] = sred[0][0][t] + sred[1][0][t];
    else
      s2g[(bh_ << 10) + nb + (t - 128)] = sred[0][1][t - 128] + sred[1][1][t - 128];
  }
}

// ---------------- tiny: s2 -> max, E=exp(s2-max) f16, F=exp(.2(s2-max)) f16 ----
__global__ __launch_bounds__(256) void k_ef(const float* __restrict__ s2g,
                                            float* __restrict__ s2m,
                                            short* __restrict__ Eh,
                                            short* __restrict__ Fh) {
  const int bh = blockIdx.x, t = threadIdx.x;
  __shared__ float red[4];
  f32x4 v = *(const f32x4*)&s2g[(bh << 10) + (t << 2)];
  float mx = fmaxf(fmaxf(v[0], v[1]), fmaxf(v[2], v[3]));
#pragma unroll
  for (int off = 1; off < 64; off <<= 1) mx = fmaxf(mx, __shfl_xor(mx, off));
  if ((t & 63) == 0) red[t >> 6] = mx;
  __syncthreads();
  const float smax = fmaxf(fmaxf(red[0], red[1]), fmaxf(red[2], red[3]));
  if (t == 0) s2m[bh] = smax;
  short4v e, f;
#pragma unroll
  for (int q = 0; q < 4; ++q) {
    e[q] = f2h(__expf(v[q] - smax));
    f[q] = f2h(__expf(0.2f * (v[q] - smax)));
  }
  *(short4v*)&Eh[(bh << 10) + (t << 2)] = e;
  *(short4v*)&Fh[(bh << 10) + (t << 2)] = f;
}

// ---------------- attention ----------------
// grid (64 bh, 8 it) -> 512 blocks, 2 blocks/CU (36 KB LDS each), 8 waves/CU.
// Wave owns a 32-row strip (m=2) x full 128 d (n=8). P in packed f16 straight
// into MFMA A-frags: p = pk_max(Ai*E, Bi*F); dsum via fdot2 (f32). Diagonal
// zeroed via per-m mask in the wave's diag tile (kk == w&1, wave-uniform).
// Hs dbuf via global_load_lds (pre-swizzled source, XOR-swizzled read).
__global__ __launch_bounds__(256) void k_attn(const short* __restrict__ hT,
                                              const float* __restrict__ s1,
                                              const short* __restrict__ Eh,
                                              const short* __restrict__ Fh,
                                              const float* __restrict__ s2max,
                                              short* __restrict__ attn) {
  __shared__ __align__(16) short Hs[2][128 * LDH];
  __shared__ __align__(16) _Float16 Esh[1024];
  __shared__ __align__(16) _Float16 Fsh[1024];
  const int bh = blockIdx.x, it = blockIdx.y;
  const int i0 = it << 7;
  const int t = threadIdx.x;
  const int w = t >> 6, lane = t & 63, lr = lane & 15, lq = lane >> 4;

  const short* hTb = hT + ((long)bh << 17);
  const int grow = (w << 5) + (lane >> 3);
  const int gcol = ((lane & 7) ^ (lane >> 3)) << 3;
  const short* gsrc = hTb + ((long)grow << 10) + gcol;

#define STAGE(buf, J0)                                             \
  do {                                                             \
    short* ldsb = &Hs[buf][(w << 5) << 6];                         \
    _Pragma("unroll") for (int i_ = 0; i_ < 4; ++i_)               \
        GLDS16(gsrc + ((long)(i_ << 3) << 10) + (J0),              \
               ldsb + ((i_ << 3) << 6));                           \
  } while (0)

  STAGE(0, 0);
  *(short4v*)&Esh[t << 2] = *(const short4v*)&Eh[(bh << 10) + (t << 2)];
  *(short4v*)&Fsh[t << 2] = *(const short4v*)&Fh[(bh << 10) + (t << 2)];

  const float smax = s2max[bh];
  f16x8 Ai8[2], Bi8[2];
  const f16x2 one2 = {(_Float16)1.f, (_Float16)1.f};
  f16x8 dmask[2];
  float dsum[2] = {0.f, 0.f};
#pragma unroll
  for (int m = 0; m < 2; ++m) {
    const int rblk = (w << 5) + (m << 4) + lr;
    float s1v = s1[(bh << 10) + i0 + rblk];
    float x = s1v + smax;
    float mi = fmaxf(x, 0.2f * x);  // upper bound of row max (lrelu monotone)
    _Float16 A_ = (_Float16)__expf(x - mi);
    _Float16 B_ = (_Float16)__expf(0.2f * x - mi);
#pragma unroll
    for (int e = 0; e < 8; ++e) { Ai8[m][e] = A_; Bi8[m][e] = B_; }
    const int lqz = ((m << 1) + (lr >> 3)) & 3, ez = lr & 7;
#pragma unroll
    for (int e = 0; e < 8; ++e)
      dmask[m][e] = (lq == lqz && e == ez) ? (_Float16)0.f : (_Float16)1.f;
  }
  const int jtd = (it << 1) + (w >> 1);  // wave-uniform diagonal j-tile
  const int kkd = w & 1;                 // wave-uniform diag k-half
  f32x4 acc[2][8] = {};
  __syncthreads();

#define TILE(buf, jt, DIAG)                                                    \
  do {                                                                         \
    _Pragma("unroll") for (int kk = 0; kk < 2; ++kk) {                         \
      const int ebase = ((jt) << 6) + (kk << 5) + (lq << 3);                   \
      f16x8 ev8 = *(const f16x8*)&Esh[ebase];                                  \
      f16x8 fv8 = *(const f16x8*)&Fsh[ebase];                                  \
      f16x8 bf[8];                                                             \
      _Pragma("unroll") for (int n = 0; n < 8; ++n) {                          \
        const int r_ = (n << 4) + lr;                                          \
        const int slot_ = ((kk << 2) + lq) ^ (r_ & 7);                         \
        bf[n] = *(const f16x8*)(&Hs[buf][(r_ << 6) + (slot_ << 3)]);           \
      }                                                                        \
      f16x8 af[2];                                                             \
      _Pragma("unroll") for (int m = 0; m < 2; ++m) {                          \
        f16x8 pm = __builtin_elementwise_max(Ai8[m] * ev8, Bi8[m] * fv8);      \
        if ((DIAG) && kk == kkd) pm = pm * dmask[m];                           \
        af[m] = pm;                                                            \
        h8u u_; u_.v = pm;                                                     \
        _Pragma("unroll") for (int p = 0; p < 4; ++p)                          \
            dsum[m] = FDOT2(u_.h[p], one2, dsum[m]);                           \
      }                                                                        \
      _Pragma("unroll") for (int m = 0; m < 2; ++m)                            \
        _Pragma("unroll") for (int n = 0; n < 8; ++n)                          \
            acc[m][n] = __builtin_amdgcn_mfma_f32_16x16x32_f16(                \
                af[m], bf[n], acc[m][n], 0, 0, 0);                             \
    }                                                                          \
  } while (0)

#pragma unroll 1
  for (int jt2 = 0; jt2 < 8; ++jt2) {
    const int jA = jt2 << 1, jB = jA | 1;
    STAGE(1, jB << 6);
    __builtin_amdgcn_s_setprio(1);
    TILE(0, jA, jA == jtd);
    __builtin_amdgcn_s_setprio(0);
    __syncthreads();
    if (jt2 < 7) STAGE(0, (jA + 2) << 6);
    __builtin_amdgcn_s_setprio(1);
    TILE(1, jB, jB == jtd);
    __builtin_amdgcn_s_setprio(0);
    __syncthreads();
  }

  const int b = bh >> 2, head = bh & 3;
#pragma unroll
  for (int m = 0; m < 2; ++m) {
    float s = dsum[m];
    s += __shfl_xor(s, 16);
    s += __shfl_xor(s, 32);  // all lq-replica lanes hold the row sum
    float rs = 1.f / s;
    f32x4 d4;
#pragma unroll
    for (int q = 0; q < 4; ++q)
      d4[q] = __shfl(rs, (lane & 48) | ((lq << 2) + q));
    int irow = i0 + (w << 5) + (m << 4) + (lq << 2);
#pragma unroll
    for (int n = 0; n < 8; ++n) {
      int d = (n << 4) + lr;
      long base = ((long)((b << 10) + irow) << 9) + (head << 7) + d;
      attn[base] = f2h(acc[m][n][0] * d4[0]);
      attn[base + 512] = f2h(acc[m][n][1] * d4[1]);
      attn[base + 1024] = f2h(acc[m][n][2] * d4[2]);
      attn[base + 1536] = f2h(acc[m][n][3] * d4[3]);
    }
  }
#undef STAGE
#undef TILE
}

// ---------------- out-proj + bias (+residual) + LN (+relu) ----------------
template <int HAS_RES, int DO_RELU, int WRITE_OUT>
__global__ __launch_bounds__(256) void k_outproj(const short* __restrict__ attn,
                                                 const short* __restrict__ WoT,
                                                 const float* __restrict__ bo,
                                                 const float* __restrict__ gamma,
                                                 const float* __restrict__ beta,
                                                 float* __restrict__ xf,
                                                 short* __restrict__ xh,
                                                 float* __restrict__ outp) {
  __shared__ __align__(16) short As[64 * LDP];
  __shared__ __align__(16) short Bs[128 * LDP];
  const int t = threadIdx.x;
  const int bn0 = blockIdx.x << 6;
  const int w = t >> 6, lane = t & 63, lr = lane & 15, lq = lane >> 4;
  f32x4 acc[8] = {};
  const int rowA = t >> 2, chA = (t & 3) << 4;
  const int rowB = t >> 1, chB = (t & 1) << 5;
  for (int k0 = 0; k0 < 512; k0 += 64) {
    {
      const short* sa = attn + ((long)(bn0 + rowA) << 9) + k0 + chA;
      short* da = As + rowA * LDP + chA;
      *(short8*)(da) = *(const short8*)(sa);
      *(short8*)(da + 8) = *(const short8*)(sa + 8);
      const short* sb = WoT + (rowB << 9) + k0 + chB;
      short* db = Bs + rowB * LDP + chB;
      *(short8*)(db) = *(const short8*)(sb);
      *(short8*)(db + 8) = *(const short8*)(sb + 8);
      *(short8*)(db + 16) = *(const short8*)(sb + 16);
      *(short8*)(db + 24) = *(const short8*)(sb + 24);
    }
    __syncthreads();
#pragma unroll
    for (int kk = 0; kk < 2; ++kk) {
      f16x8 a = *(const f16x8*)(As + ((w << 4) + lr) * LDP + (kk << 5) + (lq << 3));
#pragma unroll
      for (int n = 0; n < 8; ++n) {
        f16x8 b = *(const f16x8*)(Bs + ((n << 4) + lr) * LDP + (kk << 5) + (lq << 3));
        acc[n] = __builtin_amdgcn_mfma_f32_16x16x32_f16(a, b, acc[n], 0, 0, 0);
      }
    }
    __syncthreads();
  }
  float v[8][4], gam[8], bet[8];
#pragma unroll
  for (int n = 0; n < 8; ++n) {
    int d = (n << 4) + lr;
    float bv = bo[d];
    gam[n] = gamma[d];
    bet[n] = beta[d];
#pragma unroll
    for (int r = 0; r < 4; ++r) {
      float x = acc[n][r] + bv;
      if (HAS_RES) x += xf[((bn0 + (w << 4) + (lq << 2) + r) << 7) + d];
      v[n][r] = x;
    }
  }
#pragma unroll
  for (int r = 0; r < 4; ++r) {
    float s = 0.f, q = 0.f;
#pragma unroll
    for (int n = 0; n < 8; ++n) { s += v[n][r]; q += v[n][r] * v[n][r]; }
#pragma unroll
    for (int mk = 1; mk < 16; mk <<= 1) { s += __shfl_xor(s, mk); q += __shfl_xor(q, mk); }
    float mean = s * 0.0078125f;
    float var = q * 0.0078125f - mean * mean;
    float rstd = rsqrtf(var + 1e-5f);
    int row = bn0 + (w << 4) + (lq << 2) + r;
#pragma unroll
    for (int n = 0; n < 8; ++n) {
      int d = (n << 4) + lr;
      float o = (v[n][r] - mean) * rstd * gam[n] + bet[n];
      if (DO_RELU) o = fmaxf(o, 0.f);
      if (WRITE_OUT) {
        outp[(row << 7) + d] = o;
      } else {
        xh[(row << 7) + d] = f2h(o);
        xf[(row << 7) + d] = o;
      }
    }
  }
}

extern "C" void kernel_launch(void* const* d_in, const int* in_sizes, int n_in,
                              void* d_out, int out_size, void* d_ws, size_t ws_size,
                              hipStream_t stream) {
  const float* nf = (const float*)d_in[0];
  const float* Wp = (const float*)d_in[1];
  const float* bp = (const float*)d_in[2];
  const float* W = (const float*)d_in[3];
  const float* a1 = (const float*)d_in[4];
  const float* a2 = (const float*)d_in[5];
  const float* Wo = (const float*)d_in[6];
  const float* bo = (const float*)d_in[7];
  const float* gamma = (const float*)d_in[8];
  const float* beta = (const float*)d_in[9];
  float* outp = (float*)d_out;

  char* ws = (char*)d_ws;
  short* xh = (short*)(ws);                                    // 4 MB
  float* xf = (float*)(ws + (4ll << 20));                      // 8 MB
  short* hT = (short*)(ws + (12ll << 20));                     // 16 MB
  short* attn = (short*)(ws + (28ll << 20));                   // 16 MB
  float* s1 = (float*)(ws + (44ll << 20));                     // 256 KB
  float* s2g = (float*)(ws + (44ll << 20) + (256ll << 10));    // 256 KB
  short* Eh = (short*)(ws + (44ll << 20) + (512ll << 10));     // 128 KB
  short* Fh = (short*)(ws + (44ll << 20) + (640ll << 10));     // 128 KB
  float* s2m = (float*)(ws + (44ll << 20) + (768ll << 10));    // 1 KB
  short* WT = (short*)(ws + (45ll << 20));                     // 384 KB
  short* WoT = (short*)(ws + (45ll << 20) + 393216);           // 384 KB

  k_tw<<<1536, 256, 0, stream>>>(W, Wo, WT, WoT);
  k_inproj<<<8192, 256, 0, stream>>>(nf, Wp, bp, xh);
  for (int l = 0; l < 3; ++l) {
    k_gemm_h<<<dim3(128, 4), 256, 0, stream>>>(xh, WT + l * 65536, hT,
                                               a1 + l * 512, a2 + l * 512, s1, s2g);
    k_ef<<<64, 256, 0, stream>>>(s2g, s2m, Eh, Fh);
    k_attn<<<dim3(64, 8), 256, 0, stream>>>(hT, s1, Eh, Fh, s2m, attn);
    if (l == 0)
      k_outproj<0, 1, 0><<<256, 256, 0, stream>>>(attn, WoT + l * 65536, bo + l * 128,
                                                  gamma + l * 128, beta + l * 128, xf, xh, outp);
    else if (l == 1)
      k_outproj<1, 1, 0><<<256, 256, 0, stream>>>(attn, WoT + l * 65536, bo + l * 128,
                                                  gamma + l * 128, beta + l * 128, xf, xh, outp);
    else
      k_outproj<1, 0, 1><<<256, 256, 0, stream>>>(attn, WoT + l * 65536, bo + l * 128,
                                                  gamma + l * 128, beta + l * 128, xf, xh, outp);
  }
}

// Round 7
// 163.823 us; speedup vs baseline: 1.5201x; 1.0425x over previous
//
#include <hip/hip_runtime.h>
#include <hip/hip_bf16.h>

typedef __attribute__((ext_vector_type(8))) _Float16 f16x8;
typedef __attribute__((ext_vector_type(2))) _Float16 f16x2;
typedef __attribute__((ext_vector_type(8))) short short8;
typedef __attribute__((ext_vector_type(4))) short short4v;
typedef __attribute__((ext_vector_type(4))) float f32x4;

#define LDP 72   // LDS row stride (shorts) for reg-staged GEMM tiles
#define LDH 64   // Hs row stride (shorts): linear (global_load_lds dest)

typedef const __attribute__((address_space(1))) unsigned int* gas_ptr;
typedef __attribute__((address_space(3))) unsigned int* las_ptr;
#define GLDS16(gp, lp) \
  __builtin_amdgcn_global_load_lds((gas_ptr)(gp), (las_ptr)(lp), 16, 0, 0)

#if __has_builtin(__builtin_amdgcn_fdot2)
#define FDOT2(a, b, c) __builtin_amdgcn_fdot2((a), (b), (c), false)
#else
__device__ __forceinline__ float FDOT2(f16x2 a, f16x2 b, float c) {
  return c + (float)a[0] * (float)b[0] + (float)a[1] * (float)b[1];
}
#endif

union h8u {
  f16x8 v;
  f16x2 h[4];
};

__device__ __forceinline__ short f2h(float f) {
  union { _Float16 h; short s; } u; u.h = (_Float16)f; return u.s;
}
__device__ __forceinline__ float h2f(short s) {
  union { short s; _Float16 h; } u; u.s = s; return (float)u.h;
}

// ---------------- weight transpose + f32->f16 ----------------
__global__ __launch_bounds__(256) void k_tw(const float* __restrict__ W,
                                            const float* __restrict__ Wo,
                                            short* __restrict__ WT,
                                            short* __restrict__ WoT) {
  int idx = blockIdx.x * 256 + threadIdx.x;
  if (idx < 3 * 512 * 128) {
    int l = idx >> 16, rem = idx & 65535;
    int c = rem >> 7, k = rem & 127;
    int h = c >> 7, o = c & 127;
    WT[idx] = f2h(W[(((l * 4 + h) * 128 + k) << 7) + o]);
  } else {
    int j = idx - 3 * 512 * 128;
    int l = j >> 16, rem = j & 65535;
    int d = rem >> 9, c = rem & 511;
    WoT[j] = f2h(Wo[((l * 512 + c) << 7) + d]);
  }
}

// ---------------- input projection ----------------
__global__ __launch_bounds__(256) void k_inproj(const float* __restrict__ nf,
                                                const float* __restrict__ Wp,
                                                const float* __restrict__ bp,
                                                short* __restrict__ xh) {
  int idx = blockIdx.x * 256 + threadIdx.x;
  int bn = idx >> 7, d = idx & 127;
  float acc = bp[d];
  const float* nr = nf + bn * 7;
#pragma unroll
  for (int i = 0; i < 7; ++i) acc += nr[i] * Wp[(i << 7) + d];
  xh[idx] = f2h(acc);
}

// ---------------- head projection + fused s1/s2 ----------------
__global__ __launch_bounds__(256) void k_gemm_h(const short* __restrict__ xh,
                                                const short* __restrict__ WT,
                                                short* __restrict__ hT,
                                                const float* __restrict__ a1,
                                                const float* __restrict__ a2,
                                                float* __restrict__ s1g,
                                                float* __restrict__ s2g) {
  __shared__ __align__(16) short As[128 * LDP];
  __shared__ __align__(16) short Bs[128 * LDP];
  __shared__ float sred[2][2][128];
  const int t = threadIdx.x;
  const int bn0 = blockIdx.x << 7;
  const int head = blockIdx.y;
  const int c0 = head << 7;
  const int w = t >> 6, lane = t & 63, lr = lane & 15, lq = lane >> 4;
  const int wr = w >> 1, wc = w & 1;
  f32x4 acc[4][4] = {};
  for (int k0 = 0; k0 < 128; k0 += 64) {
    const int row = t >> 1, half = (t & 1) << 5;
    {
      const short* sa = xh + ((bn0 + row) << 7) + k0 + half;
      short* da = As + row * LDP + half;
      *(short8*)(da) = *(const short8*)(sa);
      *(short8*)(da + 8) = *(const short8*)(sa + 8);
      *(short8*)(da + 16) = *(const short8*)(sa + 16);
      *(short8*)(da + 24) = *(const short8*)(sa + 24);
      const short* sb = WT + ((c0 + row) << 7) + k0 + half;
      short* db = Bs + row * LDP + half;
      *(short8*)(db) = *(const short8*)(sb);
      *(short8*)(db + 8) = *(const short8*)(sb + 8);
      *(short8*)(db + 16) = *(const short8*)(sb + 16);
      *(short8*)(db + 24) = *(const short8*)(sb + 24);
    }
    __syncthreads();
#pragma unroll
    for (int kk = 0; kk < 2; ++kk) {
      f16x8 a[4], b[4];
#pragma unroll
      for (int m = 0; m < 4; ++m)
        a[m] = *(const f16x8*)(As + (wr * 64 + m * 16 + lr) * LDP + (kk << 5) + (lq << 3));
#pragma unroll
      for (int n = 0; n < 4; ++n)
        b[n] = *(const f16x8*)(Bs + (wc * 64 + n * 16 + lr) * LDP + (kk << 5) + (lq << 3));
#pragma unroll
      for (int m = 0; m < 4; ++m)
#pragma unroll
        for (int n = 0; n < 4; ++n)
          acc[m][n] = __builtin_amdgcn_mfma_f32_16x16x32_f16(a[m], b[n], acc[m][n], 0, 0, 0);
    }
    __syncthreads();
  }
  const int b = bn0 >> 10;
  const int nb = bn0 & 1023;
  float a1v[4], a2v[4];
#pragma unroll
  for (int n = 0; n < 4; ++n) {
    int d = wc * 64 + n * 16 + lr;
    a1v[n] = a1[(head << 7) + d];
    a2v[n] = a2[(head << 7) + d];
  }
#pragma unroll
  for (int m = 0; m < 4; ++m)
#pragma unroll
    for (int r = 0; r < 4; ++r) {
      float v1 = 0.f, v2 = 0.f;
#pragma unroll
      for (int n = 0; n < 4; ++n) {
        v1 += acc[m][n][r] * a1v[n];
        v2 += acc[m][n][r] * a2v[n];
      }
#pragma unroll
      for (int off = 1; off < 16; off <<= 1) {
        v1 += __shfl_xor(v1, off);
        v2 += __shfl_xor(v2, off);
      }
      if (lr == 0) {
        int row = wr * 64 + m * 16 + (lq << 2) + r;
        sred[wc][0][row] = v1;
        sred[wc][1][row] = v2;
      }
    }
#pragma unroll
  for (int m = 0; m < 4; ++m) {
    int nrow = nb + wr * 64 + m * 16 + (lq << 2);
#pragma unroll
    for (int n = 0; n < 4; ++n) {
      int d = wc * 64 + n * 16 + lr;
      long base = ((long)((((b << 2) + head) << 7) + d) << 10) + nrow;
      short4v v;
      v[0] = f2h(acc[m][n][0]); v[1] = f2h(acc[m][n][1]);
      v[2] = f2h(acc[m][n][2]); v[3] = f2h(acc[m][n][3]);
      *(short4v*)(hT + base) = v;
    }
  }
  __syncthreads();
  {
    const int bh_ = (b << 2) + head;
    if (t < 128)
      s1g[(bh_ << 10) + nb + t] = sred[0][0][t] + sred[1][0][t];
    else
      s2g[(bh_ << 10) + nb + (t - 128)] = sred[0][1][t - 128] + sred[1][1][t - 128];
  }
}

// ---------------- tiny: s2 -> max, E=exp(s2-max) f16, F=exp(.2(s2-max)) f16 ----
__global__ __launch_bounds__(256) void k_ef(const float* __restrict__ s2g,
                                            float* __restrict__ s2m,
                                            short* __restrict__ Eh,
                                            short* __restrict__ Fh) {
  const int bh = blockIdx.x, t = threadIdx.x;
  __shared__ float red[4];
  f32x4 v = *(const f32x4*)&s2g[(bh << 10) + (t << 2)];
  float mx = fmaxf(fmaxf(v[0], v[1]), fmaxf(v[2], v[3]));
#pragma unroll
  for (int off = 1; off < 64; off <<= 1) mx = fmaxf(mx, __shfl_xor(mx, off));
  if ((t & 63) == 0) red[t >> 6] = mx;
  __syncthreads();
  const float smax = fmaxf(fmaxf(red[0], red[1]), fmaxf(red[2], red[3]));
  if (t == 0) s2m[bh] = smax;
  short4v e, f;
#pragma unroll
  for (int q = 0; q < 4; ++q) {
    e[q] = f2h(__expf(v[q] - smax));
    f[q] = f2h(__expf(0.2f * (v[q] - smax)));
  }
  *(short4v*)&Eh[(bh << 10) + (t << 2)] = e;
  *(short4v*)&Fh[(bh << 10) + (t << 2)] = f;
}

// ---------------- attention ----------------
// grid (64 bh, 8 it). Wave owns 32-row strip (m=2) x full 128 d (n=8).
// T4-style pipeline: 3 LDS buffers, prefetch distance 2, counted
// s_waitcnt vmcnt(8) (never 0 in steady state), raw s_barrier.
__global__ __launch_bounds__(256) void k_attn(const short* __restrict__ hT,
                                              const float* __restrict__ s1,
                                              const short* __restrict__ Eh,
                                              const short* __restrict__ Fh,
                                              const float* __restrict__ s2max,
                                              short* __restrict__ attn) {
  __shared__ __align__(16) short Hs[3][128 * LDH];
  __shared__ __align__(16) _Float16 Esh[1024];
  __shared__ __align__(16) _Float16 Fsh[1024];
  const int bh = blockIdx.x, it = blockIdx.y;
  const int i0 = it << 7;
  const int t = threadIdx.x;
  const int w = t >> 6, lane = t & 63, lr = lane & 15, lq = lane >> 4;

  const short* hTb = hT + ((long)bh << 17);
  const int grow = (w << 5) + (lane >> 3);
  const int gcol = ((lane & 7) ^ (lane >> 3)) << 3;
  const short* gsrc = hTb + ((long)grow << 10) + gcol;

#define STAGE(buf, J0)                                             \
  do {                                                             \
    short* ldsb = &Hs[buf][(w << 5) << 6];                         \
    _Pragma("unroll") for (int i_ = 0; i_ < 4; ++i_)               \
        GLDS16(gsrc + ((long)(i_ << 3) << 10) + (J0),              \
               ldsb + ((i_ << 3) << 6));                           \
  } while (0)

  STAGE(0, 0);
  STAGE(1, 64);
  *(short4v*)&Esh[t << 2] = *(const short4v*)&Eh[(bh << 10) + (t << 2)];
  *(short4v*)&Fsh[t << 2] = *(const short4v*)&Fh[(bh << 10) + (t << 2)];

  const float smax = s2max[bh];
  f16x8 Ai8[2], Bi8[2];
  const f16x2 one2 = {(_Float16)1.f, (_Float16)1.f};
  f16x8 dmask[2];
  float dsum[2] = {0.f, 0.f};
#pragma unroll
  for (int m = 0; m < 2; ++m) {
    const int rblk = (w << 5) + (m << 4) + lr;
    float s1v = s1[(bh << 10) + i0 + rblk];
    float x = s1v + smax;
    float mi = fmaxf(x, 0.2f * x);  // upper bound of row max (lrelu monotone)
    _Float16 A_ = (_Float16)__expf(x - mi);
    _Float16 B_ = (_Float16)__expf(0.2f * x - mi);
#pragma unroll
    for (int e = 0; e < 8; ++e) { Ai8[m][e] = A_; Bi8[m][e] = B_; }
    const int lqz = ((m << 1) + (lr >> 3)) & 3, ez = lr & 7;
#pragma unroll
    for (int e = 0; e < 8; ++e)
      dmask[m][e] = (lq == lqz && e == ez) ? (_Float16)0.f : (_Float16)1.f;
  }
  const int jtd = (it << 1) + (w >> 1);  // wave-uniform diagonal j-tile
  const int kkd = w & 1;                 // wave-uniform diag k-half
  f32x4 acc[2][8] = {};
  __syncthreads();  // prologue: bufs 0,1 + E/F all resident

#define TILE(buf, jt, DIAG)                                                    \
  do {                                                                         \
    _Pragma("unroll") for (int kk = 0; kk < 2; ++kk) {                         \
      const int ebase = ((jt) << 6) + (kk << 5) + (lq << 3);                   \
      f16x8 ev8 = *(const f16x8*)&Esh[ebase];                                  \
      f16x8 fv8 = *(const f16x8*)&Fsh[ebase];                                  \
      f16x8 bf[8];                                                             \
      _Pragma("unroll") for (int n = 0; n < 8; ++n) {                          \
        const int r_ = (n << 4) + lr;                                          \
        const int slot_ = ((kk << 2) + lq) ^ (r_ & 7);                         \
        bf[n] = *(const f16x8*)(&Hs[buf][(r_ << 6) + (slot_ << 3)]);           \
      }                                                                        \
      f16x8 af[2];                                                             \
      _Pragma("unroll") for (int m = 0; m < 2; ++m) {                          \
        f16x8 pm = __builtin_elementwise_max(Ai8[m] * ev8, Bi8[m] * fv8);      \
        if ((DIAG) && kk == kkd) pm = pm * dmask[m];                           \
        af[m] = pm;                                                            \
        h8u u_; u_.v = pm;                                                     \
        _Pragma("unroll") for (int p = 0; p < 4; ++p)                          \
            dsum[m] = FDOT2(u_.h[p], one2, dsum[m]);                           \
      }                                                                        \
      _Pragma("unroll") for (int m = 0; m < 2; ++m)                            \
        _Pragma("unroll") for (int n = 0; n < 8; ++n)                          \
            acc[m][n] = __builtin_amdgcn_mfma_f32_16x16x32_f16(                \
                af[m], bf[n], acc[m][n], 0, 0, 0);                             \
    }                                                                          \
  } while (0)

  int cur = 0;
#pragma unroll 1
  for (int jt = 0; jt < 16; ++jt) {
    if (jt < 14) {
      STAGE((cur == 0 ? 2 : cur - 1), (jt + 2) << 6);  // (jt+2)%3
      asm volatile("s_waitcnt vmcnt(8)" ::: "memory");  // tile jt's 4 done
    } else if (jt == 14) {
      asm volatile("s_waitcnt vmcnt(4)" ::: "memory");
    } else {
      asm volatile("s_waitcnt vmcnt(0)" ::: "memory");
    }
    __builtin_amdgcn_s_barrier();   // all waves: buf[cur] fully staged
    __builtin_amdgcn_s_setprio(1);
    TILE(cur, jt, jt == jtd);
    __builtin_amdgcn_s_setprio(0);
    __builtin_amdgcn_s_barrier();   // all waves done reading buf[cur]
    cur = (cur == 2) ? 0 : cur + 1;
  }

  const int b = bh >> 2, head = bh & 3;
#pragma unroll
  for (int m = 0; m < 2; ++m) {
    float s = dsum[m];
    s += __shfl_xor(s, 16);
    s += __shfl_xor(s, 32);  // all lq-replica lanes hold the row sum
    float rs = 1.f / s;
    f32x4 d4;
#pragma unroll
    for (int q = 0; q < 4; ++q)
      d4[q] = __shfl(rs, (lane & 48) | ((lq << 2) + q));
    int irow = i0 + (w << 5) + (m << 4) + (lq << 2);
#pragma unroll
    for (int n = 0; n < 8; ++n) {
      int d = (n << 4) + lr;
      long base = ((long)((b << 10) + irow) << 9) + (head << 7) + d;
      attn[base] = f2h(acc[m][n][0] * d4[0]);
      attn[base + 512] = f2h(acc[m][n][1] * d4[1]);
      attn[base + 1024] = f2h(acc[m][n][2] * d4[2]);
      attn[base + 1536] = f2h(acc[m][n][3] * d4[3]);
    }
  }
#undef STAGE
#undef TILE
}

// ---------------- out-proj + bias (+residual) + LN (+relu) ----------------
// 32-row blocks, grid 512 (2 blocks/CU). Wave owns 16 rows x 64 cols; LN via
// cross-wave LDS partial-sum exchange.
template <int HAS_RES, int DO_RELU, int WRITE_OUT>
__global__ __launch_bounds__(256) void k_outproj(const short* __restrict__ attn,
                                                 const short* __restrict__ WoT,
                                                 const float* __restrict__ bo,
                                                 const float* __restrict__ gamma,
                                                 const float* __restrict__ beta,
                                                 float* __restrict__ xf,
                                                 short* __restrict__ xh,
                                                 float* __restrict__ outp) {
  __shared__ __align__(16) short As[32 * LDP];
  __shared__ __align__(16) short Bs[128 * LDP];
  __shared__ float sredS[2][32], sredQ[2][32];
  const int t = threadIdx.x;
  const int bn0 = blockIdx.x << 5;
  const int w = t >> 6, lane = t & 63, lr = lane & 15, lq = lane >> 4;
  const int wm = w & 1, wn = w >> 1;
  f32x4 acc[4] = {};
  const int rowA = t >> 3, chA = (t & 7) << 3;
  const int rowB = t >> 1, chB = (t & 1) << 5;
  for (int k0 = 0; k0 < 512; k0 += 64) {
    {
      const short* sa = attn + ((long)(bn0 + rowA) << 9) + k0 + chA;
      *(short8*)(As + rowA * LDP + chA) = *(const short8*)(sa);
      const short* sb = WoT + (rowB << 9) + k0 + chB;
      short* db = Bs + rowB * LDP + chB;
      *(short8*)(db) = *(const short8*)(sb);
      *(short8*)(db + 8) = *(const short8*)(sb + 8);
      *(short8*)(db + 16) = *(const short8*)(sb + 16);
      *(short8*)(db + 24) = *(const short8*)(sb + 24);
    }
    __syncthreads();
#pragma unroll
    for (int kk = 0; kk < 2; ++kk) {
      f16x8 a = *(const f16x8*)(As + ((wm << 4) + lr) * LDP + (kk << 5) + (lq << 3));
#pragma unroll
      for (int nn = 0; nn < 4; ++nn) {
        f16x8 b = *(const f16x8*)(Bs + ((wn << 6) + (nn << 4) + lr) * LDP + (kk << 5) + (lq << 3));
        acc[nn] = __builtin_amdgcn_mfma_f32_16x16x32_f16(a, b, acc[nn], 0, 0, 0);
      }
    }
    __syncthreads();
  }
  float v[4][4], gam[4], bet[4];
#pragma unroll
  for (int nn = 0; nn < 4; ++nn) {
    int d = (wn << 6) + (nn << 4) + lr;
    float bv = bo[d];
    gam[nn] = gamma[d];
    bet[nn] = beta[d];
#pragma unroll
    for (int r = 0; r < 4; ++r) {
      float x = acc[nn][r] + bv;
      if (HAS_RES) x += xf[((bn0 + (wm << 4) + (lq << 2) + r) << 7) + d];
      v[nn][r] = x;
    }
  }
  // partial row sums over this wave's 64 cols
#pragma unroll
  for (int r = 0; r < 4; ++r) {
    float s = 0.f, q = 0.f;
#pragma unroll
    for (int nn = 0; nn < 4; ++nn) { s += v[nn][r]; q += v[nn][r] * v[nn][r]; }
#pragma unroll
    for (int mk = 1; mk < 16; mk <<= 1) { s += __shfl_xor(s, mk); q += __shfl_xor(q, mk); }
    if (lr == 0) {
      int row = (wm << 4) + (lq << 2) + r;
      sredS[wn][row] = s;
      sredQ[wn][row] = q;
    }
  }
  __syncthreads();
#pragma unroll
  for (int r = 0; r < 4; ++r) {
    int rloc = (wm << 4) + (lq << 2) + r;
    float S = sredS[0][rloc] + sredS[1][rloc];
    float Q = sredQ[0][rloc] + sredQ[1][rloc];
    float mean = S * 0.0078125f;
    float var = Q * 0.0078125f - mean * mean;
    float rstd = rsqrtf(var + 1e-5f);
    int row = bn0 + rloc;
#pragma unroll
    for (int nn = 0; nn < 4; ++nn) {
      int d = (wn << 6) + (nn << 4) + lr;
      float o = (v[nn][r] - mean) * rstd * gam[nn] + bet[nn];
      if (DO_RELU) o = fmaxf(o, 0.f);
      if (WRITE_OUT) {
        outp[(row << 7) + d] = o;
      } else {
        xh[(row << 7) + d] = f2h(o);
        xf[(row << 7) + d] = o;
      }
    }
  }
}

extern "C" void kernel_launch(void* const* d_in, const int* in_sizes, int n_in,
                              void* d_out, int out_size, void* d_ws, size_t ws_size,
                              hipStream_t stream) {
  const float* nf = (const float*)d_in[0];
  const float* Wp = (const float*)d_in[1];
  const float* bp = (const float*)d_in[2];
  const float* W = (const float*)d_in[3];
  const float* a1 = (const float*)d_in[4];
  const float* a2 = (const float*)d_in[5];
  const float* Wo = (const float*)d_in[6];
  const float* bo = (const float*)d_in[7];
  const float* gamma = (const float*)d_in[8];
  const float* beta = (const float*)d_in[9];
  float* outp = (float*)d_out;

  char* ws = (char*)d_ws;
  short* xh = (short*)(ws);                                    // 4 MB
  float* xf = (float*)(ws + (4ll << 20));                      // 8 MB
  short* hT = (short*)(ws + (12ll << 20));                     // 16 MB
  short* attn = (short*)(ws + (28ll << 20));                   // 16 MB
  float* s1 = (float*)(ws + (44ll << 20));                     // 256 KB
  float* s2g = (float*)(ws + (44ll << 20) + (256ll << 10));    // 256 KB
  short* Eh = (short*)(ws + (44ll << 20) + (512ll << 10));     // 128 KB
  short* Fh = (short*)(ws + (44ll << 20) + (640ll << 10));     // 128 KB
  float* s2m = (float*)(ws + (44ll << 20) + (768ll << 10));    // 1 KB
  short* WT = (short*)(ws + (45ll << 20));                     // 384 KB
  short* WoT = (short*)(ws + (45ll << 20) + 393216);           // 384 KB

  k_tw<<<1536, 256, 0, stream>>>(W, Wo, WT, WoT);
  k_inproj<<<8192, 256, 0, stream>>>(nf, Wp, bp, xh);
  for (int l = 0; l < 3; ++l) {
    k_gemm_h<<<dim3(128, 4), 256, 0, stream>>>(xh, WT + l * 65536, hT,
                                               a1 + l * 512, a2 + l * 512, s1, s2g);
    k_ef<<<64, 256, 0, stream>>>(s2g, s2m, Eh, Fh);
    k_attn<<<dim3(64, 8), 256, 0, stream>>>(hT, s1, Eh, Fh, s2m, attn);
    if (l == 0)
      k_outproj<0, 1, 0><<<512, 256, 0, stream>>>(attn, WoT + l * 65536, bo + l * 128,
                                                  gamma + l * 128, beta + l * 128, xf, xh, outp);
    else if (l == 1)
      k_outproj<1, 1, 0><<<512, 256, 0, stream>>>(attn, WoT + l * 65536, bo + l * 128,
                                                  gamma + l * 128, beta + l * 128, xf, xh, outp);
    else
      k_outproj<1, 0, 1><<<512, 256, 0, stream>>>(attn, WoT + l * 65536, bo + l * 128,
                                                  gamma + l * 128, beta + l * 128, xf, xh, outp);
  }
}